// Round 7
// baseline (916.835 us; speedup 1.0000x reference)
//
#include <hip/hip_runtime.h>
#include <hip/hip_bf16.h>

// Block_ViT on MI355X — round 19:
// (a) mfma4 rebuilt: BK=32, 3 LDS slots (48 KB -> 3 blocks/CU, was 2), same
//     per-phase recipe {ds_read cur || stage(t+2) -> bar -> lgkm0 -> setprio
//     16 MFMA -> counted vmcnt -> bar}. vmcnt derived from ACTUALLY-issued
//     cp16s (pend 0/2/4) — also fixes latent K-tail under-drain race.
// (b) XCD partition now 2D (4 n-groups x 2 m-groups) where grid%8==0:
//     KV-proj (gx padded 30->32), FFN1@512/@256, Wo/FFN2@512. R18's 1D m-major
//     chunking refetched B per-XCD (FETCH 62.8MB ~= 8B+A, model-confirmed);
//     2D gives 4A+2B ~= 39MB and ~L2-resident per-XCD working sets.
// B=4, N=784, H=4, Cs={64,128,256,512}, KV=960, NT=3136. fp32 in/out.

using bf16 = __hip_bfloat16;
typedef __attribute__((ext_vector_type(8))) short short8;   // 8 bf16 (4 VGPRs)
typedef __attribute__((ext_vector_type(4))) float f32x4;    // MFMA acc

__device__ inline float bf2f(unsigned short u) {
    return __uint_as_float(((unsigned int)u) << 16);
}
__device__ inline unsigned short f2b(float f) {            // RTNE fp32->bf16
    unsigned int u = __float_as_uint(f);
    return (unsigned short)((u + 0x7fffu + ((u >> 16) & 1u)) >> 16);
}
__device__ inline float ld1f(const float* p) { return *p; }
__device__ inline float ld1f(const bf16* p) { return bf2f(*(const unsigned short*)p); }
__device__ inline void st1(float* p, float v) { *p = v; }
__device__ inline void st1(bf16* p, float v) { *((unsigned short*)p) = f2b(v); }
__device__ inline float4 ld4f(const bf16* p) {
    ushort4 u = *(const ushort4*)p;
    return make_float4(bf2f(u.x), bf2f(u.y), bf2f(u.z), bf2f(u.w));
}

// async global->LDS, 16 B per lane; LDS dest = wave-uniform base + lane*16
__device__ __forceinline__ void cp16(const void* g, void* l) {
    __builtin_amdgcn_global_load_lds(
        (const __attribute__((address_space(1))) void*)g,
        (__attribute__((address_space(3))) void*)l, 16, 0, 0);
}

// ---- block reductions (256 threads = 4 waves) ----
__device__ inline float blockSum256(float v, float* red) {
    #pragma unroll
    for (int o = 32; o > 0; o >>= 1) v += __shfl_down(v, o);
    int t = threadIdx.x;
    if ((t & 63) == 0) red[t >> 6] = v;
    __syncthreads();
    float r = red[0] + red[1] + red[2] + red[3];
    __syncthreads();
    return r;
}
__device__ inline float blockMax256(float v, float* red) {
    #pragma unroll
    for (int o = 32; o > 0; o >>= 1) v = fmaxf(v, __shfl_down(v, o));
    int t = threadIdx.x;
    if ((t & 63) == 0) red[t >> 6] = v;
    __syncthreads();
    float r = fmaxf(fmaxf(red[0], red[1]), fmaxf(red[2], red[3]));
    __syncthreads();
    return r;
}

// ---- fp32 -> bf16 weight conversion + optional stat zeroing ----
struct Cvt4 {
    const float* s[4];
    unsigned short* d[4];
    long n[4];
    float* z32;           // if non-null: zero 32 floats (IN stats accumulator)
};
__global__ __launch_bounds__(256)
void cvt_kernel(Cvt4 a) {
    if (a.z32 && blockIdx.x == 0 && threadIdx.x < 32) a.z32[threadIdx.x] = 0.f;
    long tid = (long)blockIdx.x * 256 + threadIdx.x;
    long stride = (long)gridDim.x * 256;
    for (int g = 0; g < 4; g++) {
        const float* s = a.s[g];
        if (!s) continue;
        unsigned short* d = a.d[g];
        long n = a.n[g];
        for (long i = tid * 4; i < n; i += stride * 4) {
            float4 v = *(const float4*)(s + i);
            *(ushort4*)(d + i) = make_ushort4(f2b(v.x), f2b(v.y), f2b(v.z), f2b(v.w));
        }
    }
}

// ==== mfma4: 128x128 tile, 4 waves (2Mx2N), BK=32, 1 phase/K-step, 3 slots ====
// REQUIRES K >= 128, K % 8 == 0, Mpad/Npad % 128 == 0, all rows < Mpad/Npad
// READABLE (pads may be garbage; stores masked by M/N).
// XCD remap: qx>0 -> 2D partition (grid MUST be (4*qx, 2*hy, 1), nwg%8==0):
//   XCD c owns n-quarter c&3, m-half c>>2 -> HBM fetch = 4A+2B, working set
//   ~fits per-XCD L2. qx==0 -> 1D m204 bijective chunking.
// LDS per operand: [3 slots][128 rows][32 shorts] = 24 KB; 48 KB total ->
// 3 blocks/CU. Swizzle hash h(r)=(r>>1)&3 (R13-proven, 0 conflicts).
// Pipeline per K-step kt: {ds_read slot kt%3 || stage(kt+2) -> s_barrier ->
// lgkm0+sched_barrier -> setprio 16 MFMA -> vmcnt(pend) -> s_barrier};
// pend = cp16s issued THIS phase (0/2/4) so the wait always fully drains
// stage(kt+1) regardless of K-tails / slow paths.
template <class CT, class RT, bool TO>
__global__ __launch_bounds__(256, 3)
void mfma4(const bf16* __restrict__ A, long Ah, long Ab, int lda,
           const bf16* __restrict__ B, long Bh, long Bb, int ldb,
           CT* __restrict__ Cp, long Ch, long Cb, int ldc,
           const float* __restrict__ bias, const RT* __restrict__ res,
           int M, int N, int K, int Mpad, int Npad, int qx, int hy,
           float alpha, int dogelu, float* __restrict__ stat) {
    __shared__ short Asl[3][128][32];
    __shared__ short Bsl[3][128][32];
    // ---- XCD-aware block remap ----
    int gx = gridDim.x, gy = gridDim.y;
    int orig = ((int)blockIdx.z * gy + (int)blockIdx.y) * gx + (int)blockIdx.x;
    int bx, by, bz;
    if (qx) {                       // 2D: grid (4*qx, 2*hy, 1), nwg%8==0
        int c = orig & 7, r2 = orig >> 3;
        bx = (c & 3) * qx + r2 % qx;
        by = (c >> 2) * hy + r2 / qx;
        bz = 0;
    } else {                        // 1D m204 bijective
        int nxy = gx * gy, nwg = nxy * (int)gridDim.z;
        int q = nwg >> 3, r8 = nwg & 7;
        int xcd = orig & 7, pos = orig >> 3;
        int wgid = (xcd < r8 ? xcd * (q + 1) : r8 * (q + 1) + (xcd - r8) * q) + pos;
        bz = wgid / nxy;
        int rem = wgid - bz * nxy;
        by = rem / gx; bx = rem - by * gx;
    }
    int z = bz;
    A += (long)(z & 3) * Ah + (long)(z >> 2) * Ab;
    B += (long)(z & 3) * Bh + (long)(z >> 2) * Bb;
    Cp += (long)(z & 3) * Ch + (long)(z >> 2) * Cb;
    int m0 = by * 128, n0 = bx * 128;
    int t = threadIdx.x, lane = t & 63, wv = t >> 6;   // wv 0..3
    int col = lane & 15, quad = lane >> 4;
    int wm = wv >> 1, wn = wv & 1;                     // 2(M) x 2(N)
    f32x4 acc[4][4];
    #pragma unroll
    for (int i = 0; i < 4; i++)
        #pragma unroll
        for (int j = 0; j < 4; j++) acc[i][j] = (f32x4){0.f, 0.f, 0.f, 0.f};

    const bool fA = (m0 + 128 <= Mpad);
    const bool fB = (n0 + 128 <= Npad);
    int srow = lane >> 2;
    int scol = ((lane & 3) ^ ((lane >> 3) & 3)) << 3;
    int rslot = (quad ^ ((col >> 1) & 3)) << 3;

    auto stageA = [&](int s3, int kt) {
        int k0 = kt * 32;
        if (fA && k0 + 32 <= K) {
            #pragma unroll
            for (int r = 0; r < 2; r++) {
                int R0 = (r * 4 + wv) * 16;
                cp16(A + (long)(m0 + R0 + srow) * lda + k0 + scol, &Asl[s3][R0][0]);
            }
        } else {
            #pragma unroll
            for (int r = 0; r < 2; r++) {
                int idx = r * 256 + t;
                int row = idx >> 2, sl = idx & 3;
                int f2 = (row >> 1) & 3;
                short8 v = {};
                if (m0 + row < M && k0 + sl * 8 < K)   // K%8==0 at all call sites
                    v = *(const short8*)(A + (long)(m0 + row) * lda + k0 + sl * 8);
                *(short8*)&Asl[s3][row][(sl ^ f2) * 8] = v;
            }
            asm volatile("s_waitcnt lgkmcnt(0)" ::: "memory");
        }
    };
    auto stageB = [&](int s3, int kt) {
        int k0 = kt * 32;
        if (fB && k0 + 32 <= K) {
            #pragma unroll
            for (int r = 0; r < 2; r++) {
                int R0 = (r * 4 + wv) * 16;
                cp16(B + (long)(n0 + R0 + srow) * ldb + k0 + scol, &Bsl[s3][R0][0]);
            }
        } else {
            #pragma unroll
            for (int r = 0; r < 2; r++) {
                int idx = r * 256 + t;
                int row = idx >> 2, sl = idx & 3;
                int f2 = (row >> 1) & 3;
                short8 v = {};
                if (n0 + row < N && k0 + sl * 8 < K)
                    v = *(const short8*)(B + (long)(n0 + row) * ldb + k0 + sl * 8);
                *(short8*)&Bsl[s3][row][(sl ^ f2) * 8] = v;
            }
            asm volatile("s_waitcnt lgkmcnt(0)" ::: "memory");
        }
    };

    int nk = (K + 31) >> 5;          // K >= 128 -> nk >= 4
    stageA(0, 0); stageB(0, 0);
    stageA(1, 1); stageB(1, 1);
    __syncthreads();                 // drains vmcnt+lgkm: tiles 0,1 resident

    for (int kt = 0; kt < nk; kt++) {
        int cur = kt % 3;
        short8 af[4], bf4[4];
        #pragma unroll
        for (int mi = 0; mi < 4; mi++)
            af[mi] = *(const short8*)&Asl[cur][wm * 64 + mi * 16 + col][rslot];
        #pragma unroll
        for (int ni = 0; ni < 4; ni++)
            bf4[ni] = *(const short8*)&Bsl[cur][wn * 64 + ni * 16 + col][rslot];
        int pend = 0;
        if (kt + 2 < nk) {
            int s3 = (kt + 2) % 3;
            stageA(s3, kt + 2); stageB(s3, kt + 2);
            if ((kt + 2) * 32 + 32 <= K) pend = (fA ? 2 : 0) + (fB ? 2 : 0);
        }
        __builtin_amdgcn_s_barrier();
        asm volatile("s_waitcnt lgkmcnt(0)" ::: "memory");
        __builtin_amdgcn_sched_barrier(0);
        __builtin_amdgcn_s_setprio(1);
        #pragma unroll
        for (int mi = 0; mi < 4; mi++)
            #pragma unroll
            for (int ni = 0; ni < 4; ni++)
                acc[mi][ni] = __builtin_amdgcn_mfma_f32_16x16x32_bf16(
                    af[mi], bf4[ni], acc[mi][ni], 0, 0, 0);
        __builtin_amdgcn_s_setprio(0);
        if (kt + 1 < nk) {
            // drain stage(kt+1) fully; keep this phase's pend in flight
            if (pend == 4)      asm volatile("s_waitcnt vmcnt(4)" ::: "memory");
            else if (pend == 2) asm volatile("s_waitcnt vmcnt(2)" ::: "memory");
            else                asm volatile("s_waitcnt vmcnt(0)" ::: "memory");
            __builtin_amdgcn_s_barrier();
        }
    }
    // epilogue — C/D layout: col=lane&15, row=quad*4+reg [m89/m91]
    float psum = 0.f, psq = 0.f;
    #pragma unroll
    for (int mi = 0; mi < 4; mi++) {
        int gmB = m0 + wm * 64 + mi * 16 + quad * 4;
        #pragma unroll
        for (int ni = 0; ni < 4; ni++) {
            int gn = n0 + wn * 64 + ni * 16 + col;
            if constexpr (TO) {
                if (gmB < M && gn < N) {
                    ushort4 w = make_ushort4(f2b(acc[mi][ni][0] * alpha),
                                             f2b(acc[mi][ni][1] * alpha),
                                             f2b(acc[mi][ni][2] * alpha),
                                             f2b(acc[mi][ni][3] * alpha));
                    *(ushort4*)((unsigned short*)Cp + (long)gn * ldc + gmB) = w;
                }
            } else {
                if (gn < N) {
                    float bz2 = bias ? bias[gn] : 0.f;
                    #pragma unroll
                    for (int r = 0; r < 4; r++) {
                        int gm = gmB + r;
                        if (gm < M) {
                            float v = acc[mi][ni][r] * alpha + bz2;
                            if (dogelu) v = 0.5f * v * (1.f + erff(v * 0.70710678118f));
                            if (res) v += ld1f(res + (long)gm * ldc + gn);
                            st1(Cp + (long)gm * ldc + gn, v);
                            psum += v; psq += v * v;
                        }
                    }
                }
            }
        }
    }
    if (stat) {   // fused InstanceNorm partial stats, one atomicAdd pair/block
        __syncthreads();
        #pragma unroll
        for (int o = 32; o > 0; o >>= 1) {
            psum += __shfl_down(psum, o);
            psq  += __shfl_down(psq, o);
        }
        float* red = (float*)Asl;
        if ((t & 63) == 0) { red[wv] = psum; red[4 + wv] = psq; }
        __syncthreads();
        if (t == 0) {
            atomicAdd(&stat[2 * z],     red[0] + red[1] + red[2] + red[3]);
            atomicAdd(&stat[2 * z + 1], red[4] + red[5] + red[6] + red[7]);
        }
    }
}

// ==== mfma2 (R13 form) + optional fused stats — C=64 branch only ====
template <int TM, int TN, class CT, class RT, bool TO>
__global__ __launch_bounds__(256)
void mfma2(const bf16* __restrict__ A, long Ah, long Ab, int lda,
           const bf16* __restrict__ B, long Bh, long Bb, int ldb,
           CT* __restrict__ Cp, long Ch, long Cb, int ldc,
           const float* __restrict__ bias, const RT* __restrict__ res,
           int M, int N, int K, float alpha, int dogelu,
           float* __restrict__ stat) {
    constexpr int MI = TM / 32, NI = TN / 32;
    __shared__ short As[2][TM * 32];
    __shared__ short Bs[2][TN * 32];
    int z = blockIdx.z;
    A += (long)(z & 3) * Ah + (long)(z >> 2) * Ab;
    B += (long)(z & 3) * Bh + (long)(z >> 2) * Bb;
    Cp += (long)(z & 3) * Ch + (long)(z >> 2) * Cb;
    int m0 = blockIdx.y * TM, n0 = blockIdx.x * TN;
    int t = threadIdx.x, lane = t & 63, wv = t >> 6;
    int col = lane & 15, quad = lane >> 4;
    int wm = wv >> 1, wn = wv & 1;
    f32x4 acc[MI][NI];
    #pragma unroll
    for (int i = 0; i < MI; i++)
        #pragma unroll
        for (int j = 0; j < NI; j++) acc[i][j] = (f32x4){0.f, 0.f, 0.f, 0.f};

    const bool fastblk = (m0 + TM <= M) && (n0 + TN <= N);
    int lrow = lane >> 2;
    int lcol = ((lane & 3) ^ ((lane >> 3) & 3)) << 3;
    int sr = t >> 2;
    int swz = ((t & 3) ^ ((t >> 3) & 3)) << 3;
    int sdst = (t & 3) << 3;
    int rdslot = (quad ^ ((col >> 1) & 3)) << 3;

    auto stage = [&](int b, int k0) {
        if (fastblk && (k0 + 32 <= K)) {
            #pragma unroll
            for (int u = 0; u < TM / 64; u++) {
                int c = wv + 4 * u;
                int r = c * 16 + lrow;
                cp16(A + (long)(m0 + r) * lda + k0 + lcol, &As[b][c * 512]);
            }
            #pragma unroll
            for (int u = 0; u < TN / 64; u++) {
                int c = wv + 4 * u;
                int r = c * 16 + lrow;
                cp16(B + (long)(n0 + r) * ldb + k0 + lcol, &Bs[b][c * 512]);
            }
        } else {
            #pragma unroll
            for (int u = 0; u < TM / 64; u++) {
                int r = sr + u * 64;
                float4 v = make_float4(0.f, 0.f, 0.f, 0.f);
                if (m0 + r < M && k0 + swz < K)
                    v = *(const float4*)(A + (long)(m0 + r) * lda + k0 + swz);
                *(float4*)&As[b][r * 32 + sdst] = v;
            }
            #pragma unroll
            for (int u = 0; u < TN / 64; u++) {
                int r = sr + u * 64;
                float4 v = make_float4(0.f, 0.f, 0.f, 0.f);
                if (n0 + r < N && k0 + swz < K)
                    v = *(const float4*)(B + (long)(n0 + r) * ldb + k0 + swz);
                *(float4*)&Bs[b][r * 32 + sdst] = v;
            }
        }
    };

    int nk = (K + 31) >> 5;
    stage(0, 0);
    __syncthreads();
    int cur = 0;
    for (int s = 0; s < nk; s++) {
        if (s + 1 < nk) stage(cur ^ 1, (s + 1) * 32);
        short8 af[MI], bfr[NI];
        #pragma unroll
        for (int mi = 0; mi < MI; mi++)
            af[mi] = *(const short8*)&As[cur][(wm * (TM / 2) + mi * 16 + col) * 32 + rdslot];
        #pragma unroll
        for (int ni = 0; ni < NI; ni++)
            bfr[ni] = *(const short8*)&Bs[cur][(wn * (TN / 2) + ni * 16 + col) * 32 + rdslot];
        #pragma unroll
        for (int mi = 0; mi < MI; mi++)
            #pragma unroll
            for (int ni = 0; ni < NI; ni++)
                acc[mi][ni] = __builtin_amdgcn_mfma_f32_16x16x32_bf16(
                    af[mi], bfr[ni], acc[mi][ni], 0, 0, 0);
        if (s + 1 < nk) __syncthreads();
        cur ^= 1;
    }
    float psum = 0.f, psq = 0.f;
    #pragma unroll
    for (int mi = 0; mi < MI; mi++) {
        int gmB = m0 + wm * (TM / 2) + mi * 16 + quad * 4;
        #pragma unroll
        for (int ni = 0; ni < NI; ni++) {
            int gn = n0 + wn * (TN / 2) + ni * 16 + col;
            if constexpr (TO) {
                if (gmB < M && gn < N) {
                    ushort4 w = make_ushort4(f2b(acc[mi][ni][0] * alpha),
                                             f2b(acc[mi][ni][1] * alpha),
                                             f2b(acc[mi][ni][2] * alpha),
                                             f2b(acc[mi][ni][3] * alpha));
                    *(ushort4*)((unsigned short*)Cp + (long)gn * ldc + gmB) = w;
                }
            } else {
                if (gn < N) {
                    float bz = bias ? bias[gn] : 0.f;
                    #pragma unroll
                    for (int r = 0; r < 4; r++) {
                        int gm = gmB + r;
                        if (gm < M) {
                            float v = acc[mi][ni][r] * alpha + bz;
                            if (dogelu) v = 0.5f * v * (1.f + erff(v * 0.70710678118f));
                            if (res) v += ld1f(res + (long)gm * ldc + gn);
                            st1(Cp + (long)gm * ldc + gn, v);
                            psum += v; psq += v * v;
                        }
                    }
                }
            }
        }
    }
    if (stat) {
        __syncthreads();
        #pragma unroll
        for (int o = 32; o > 0; o >>= 1) {
            psum += __shfl_down(psum, o);
            psq  += __shfl_down(psq, o);
        }
        float* red = (float*)As;
        if ((t & 63) == 0) { red[wv] = psum; red[4 + wv] = psq; }
        __syncthreads();
        if (t == 0) {
            atomicAdd(&stat[2 * z],     red[0] + red[1] + red[2] + red[3]);
            atomicAdd(&stat[2 * z + 1], red[4] + red[5] + red[6] + red[7]);
        }
    }
}

// ---- merged LayerNorms: concat-LN (ea) + 4 branch first-LNs, one emb read ----
struct LNA {
    const float* e[4];
    const float* ag[4];
    const float* ab[4];
    const float* cg;
    const float* cbb;
    bf16* y[4];
    bf16* ea;
};
__global__ __launch_bounds__(256)
void ln_all_kernel(LNA a) {
    __shared__ float x[960];
    __shared__ float red[4];
    long row = blockIdx.x;
    int t = threadIdx.x;
    const int off[5] = {0, 64, 192, 448, 960};
    {
        const float* p1 = a.e[0] + row * 64;
        const float* p2 = a.e[1] + row * 128;
        const float* p3 = a.e[2] + row * 256;
        const float* p4 = a.e[3] + row * 512;
        if (t < 64) x[t] = p1[t];
        for (int i = t; i < 128; i += 256) x[64 + i]  = p2[i];
        for (int i = t; i < 256; i += 256) x[192 + i] = p3[i];
        for (int i = t; i < 512; i += 256) x[448 + i] = p4[i];
    }
    __syncthreads();
    float ssum[4], ssq[4];
    #pragma unroll
    for (int br = 0; br < 4; br++) {
        float s = 0.f, q = 0.f;
        for (int i = off[br] + t; i < off[br + 1]; i += 256) {
            float v = x[i]; s += v; q += v * v;
        }
        ssum[br] = blockSum256(s, red);
        ssq[br]  = blockSum256(q, red);
    }
    float S1 = ssum[0] + ssum[1] + ssum[2] + ssum[3];
    float S2 = ssq[0] + ssq[1] + ssq[2] + ssq[3];
    float muA = S1 * (1.f / 960.f);
    float rA = rsqrtf(S2 * (1.f / 960.f) - muA * muA + 1e-6f);
    for (int i = t; i < 960; i += 256)
        st1(a.ea + row * 960 + i, (x[i] - muA) * rA * a.cg[i] + a.cbb[i]);
    #pragma unroll
    for (int br = 0; br < 4; br++) {
        int C = off[br + 1] - off[br];
        float mu = ssum[br] / C;
        float rr = rsqrtf(ssq[br] / C - mu * mu + 1e-6f);
        const float* g = a.ag[br];
        const float* b = a.ab[br];
        bf16* y = a.y[br] + row * C;
        for (int i = t; i < C; i += 256)
            st1(y + i, (x[off[br] + i] - mu) * rr * g[i] + b[i]);
    }
}

// ---- row LayerNorm (bf16 in) -> bf16 ----
__global__ __launch_bounds__(256)
void ln_rows_kernel(const bf16* __restrict__ X, const float* __restrict__ g,
                    const float* __restrict__ b, bf16* __restrict__ Y, int C) {
    __shared__ float x[512];
    __shared__ float red[4];
    long row = blockIdx.x;
    int t = threadIdx.x;
    const bf16* xr = X + row * C;
    float s = 0.f, q = 0.f;
    for (int i = t; i < C; i += 256) { float v = ld1f(xr + i); x[i] = v; s += v; q += v * v; }
    float S1 = blockSum256(s, red), S2 = blockSum256(q, red);
    float mu = S1 / C;
    float r = rsqrtf(S2 / C - mu * mu + 1e-6f);
    for (int i = t; i < C; i += 256)
        st1(Y + row * C + i, (x[i] - mu) * r * g[i] + b[i]);
}

// ---- ctx head-sum: ctx[i] = 0.25*sum_h tmp[h][i] ----
__global__ __launch_bounds__(256)
void ctx_sum_kernel(const bf16* __restrict__ tmp, bf16* __restrict__ ctx, long NTC) {
    long i = ((long)blockIdx.x * 256 + threadIdx.x) * 4;
    float4 a = ld4f(tmp + i);
    float4 b = ld4f(tmp + NTC + i);
    float4 c = ld4f(tmp + 2 * NTC + i);
    float4 d = ld4f(tmp + 3 * NTC + i);
    ushort4 o = make_ushort4(f2b((a.x + b.x + c.x + d.x) * 0.25f),
                             f2b((a.y + b.y + c.y + d.y) * 0.25f),
                             f2b((a.z + b.z + c.z + d.z) * 0.25f),
                             f2b((a.w + b.w + c.w + d.w) * 0.25f));
    *(ushort4*)(ctx + i) = o;
}

// ---- softmax over last dim (960) of S2[b][C][4*960]; rstd from fused stats ----
__global__ __launch_bounds__(256)
void softmax_kernel(bf16* __restrict__ S, const float* __restrict__ stat, int C) {
    __shared__ float x[960];
    __shared__ float red[4];
    long r = blockIdx.x;
    int t = threadIdx.x;
    int z = (int)(r / C);           // stats z: z&3=h, z>>2=b (matches S-GEMM)
    int d = (int)(r % C);
    float n = 960.f * (float)C;
    float s0 = stat[2 * z], q0 = stat[2 * z + 1];
    float mu = s0 / n;
    float rs = rsqrtf(q0 / n - mu * mu + 1e-5f);
    int h = z & 3, b = z >> 2;
    bf16* row = S + (long)b * C * 3840 + (long)d * 3840 + h * 960;
    float mx = -3.4e38f;
    for (int i = t; i < 960; i += 256) {
        float v = ld1f(row + i) * rs; x[i] = v; mx = fmaxf(mx, v);
    }
    float M = blockMax256(mx, red);
    float s = 0.f;
    for (int i = t; i < 960; i += 256) { float e = __expf(x[i] - M); x[i] = e; s += e; }
    float Ssum = blockSum256(s, red);
    float inv = 1.f / Ssum;
    for (int i = t; i < 960; i += 256) st1(row + i, x[i] * inv);
}

extern "C" void kernel_launch(void* const* d_in, const int* in_sizes, int n_in,
                              void* d_out, int out_size, void* d_ws, size_t ws_size,
                              hipStream_t stream) {
    (void)in_sizes; (void)n_in; (void)out_size; (void)ws_size;
    const int Cs[4] = {64, 128, 256, 512};
    const float *emb[4], *ang[4], *anb[4], *Wq[4], *Wo[4], *fng[4], *fnb[4], *w1[4], *b1[4], *w2[4], *b2[4];
    for (int i = 0; i < 4; i++) {
        const int base = i * 11;
        emb[i] = (const float*)d_in[base + 0];
        ang[i] = (const float*)d_in[base + 1];
        anb[i] = (const float*)d_in[base + 2];
        Wq[i]  = (const float*)d_in[base + 3];
        Wo[i]  = (const float*)d_in[base + 4];
        fng[i] = (const float*)d_in[base + 5];
        fnb[i] = (const float*)d_in[base + 6];
        w1[i]  = (const float*)d_in[base + 7];
        b1[i]  = (const float*)d_in[base + 8];
        w2[i]  = (const float*)d_in[base + 9];
        b2[i]  = (const float*)d_in[base + 10];
    }
    const float* anAg = (const float*)d_in[44];
    const float* anAb = (const float*)d_in[45];
    const float* Wk   = (const float*)d_in[46];
    const float* Wv   = (const float*)d_in[47];

    const int NT = 3136;
    char* wsb = (char*)d_ws;
    bf16*   ea    = (bf16*)(wsb);                    // [3136,960] (+pad reads OK)
    bf16*   KT    = (bf16*)(wsb + 6021120);          // [3840][3136]
    bf16*   Vb2   = (bf16*)(wsb + 30105600);         // [3136][3840] head-concat V
    bf16*   Qb    = (bf16*)(wsb + 54190080);         // QT / per-head tmp / hid
    bf16*   Sb    = (bf16*)(wsb + 67035136);         // S2 [b][C][3840]; wk/wv early
    bf16*   cxall = (bf16*)(wsb + 82763776);         // first-LN out, all branches
    bf16*   cxb   = (bf16*)(wsb + 88784896);         // ctx / post-res LN
    bf16*   xb    = (bf16*)(wsb + 91996160);         // residual
    bf16*   wtb   = (bf16*)(wsb + 95207424);         // per-branch weights, reused
    float*  statb = (float*)(wsb + 102023168);       // [32] IN sum/sumsq per z

    bf16* wkb = Sb;                 // Sb region free until branch-0 scores
    bf16* wvb = Sb + 3686400;       // wkb/wvb contiguous: [3840][960] each
    const long cxoff[4] = {0, 64L * NT, 192L * NT, 448L * NT};

    float* out = (float*)d_out;
    const long ooff[4] = {0, 200704, 602112, 1404928};
    const float scale = 0.03227486121f;  // 1/sqrt(960)

    {
        Cvt4 a;
        a.s[0] = Wk; a.d[0] = (unsigned short*)wkb; a.n[0] = 3686400;
        a.s[1] = Wv; a.d[1] = (unsigned short*)wvb; a.n[1] = 3686400;
        a.s[2] = nullptr; a.s[3] = nullptr; a.d[2] = a.d[3] = nullptr; a.n[2] = a.n[3] = 0;
        a.z32 = nullptr;
        cvt_kernel<<<512, 256, 0, stream>>>(a);
    }
    {
        LNA a;
        for (int i = 0; i < 4; i++) {
            a.e[i] = emb[i]; a.ag[i] = ang[i]; a.ab[i] = anb[i];
            a.y[i] = cxall + cxoff[i];
        }
        a.cg = anAg; a.cbb = anAb; a.ea = ea;
        ln_all_kernel<<<3136, 256, 0, stream>>>(a);
    }
    // K-proj: KT = (ea @ Wk_all^T)^T — grid padded (32,26), 2D XCD qx=8 hy=13
    mfma4<bf16, float, true><<<dim3(32, 26, 1), 256, 0, stream>>>(
        ea, 0, 0, 960, wkb, 0, 0, 960, KT, 0, 0, NT,
        nullptr, (const float*)nullptr, NT, 3840, 960, 3328, 4096, 8, 13,
        1.f, 0, nullptr);
    // V-proj: Vb2[n][h*960+j] — same 2D partition
    mfma4<bf16, float, false><<<dim3(32, 26, 1), 256, 0, stream>>>(
        ea, 0, 0, 960, wvb, 0, 0, 960, Vb2, 0, 0, 3840,
        nullptr, (const float*)nullptr, NT, 3840, 960, 3328, 4096, 8, 13,
        1.f, 0, nullptr);

    for (int i = 0; i < 4; i++) {
        const int C = Cs[i];
        const long C2 = (long)C * C;
        bf16* wqb = wtb;
        bf16* wob = wtb + 4 * C2;
        bf16* w1b = wtb + 5 * C2;
        bf16* w2b = wtb + 9 * C2;
        {
            Cvt4 a;
            a.s[0] = Wq[i]; a.d[0] = (unsigned short*)wqb; a.n[0] = 4 * C2;
            a.s[1] = Wo[i]; a.d[1] = (unsigned short*)wob; a.n[1] = C2;
            a.s[2] = w1[i]; a.d[2] = (unsigned short*)w1b; a.n[2] = 4 * C2;
            a.s[3] = w2[i]; a.d[3] = (unsigned short*)w2b; a.n[3] = 4 * C2;
            a.z32 = statb;                 // zero IN stats for this branch
            cvt_kernel<<<512, 256, 0, stream>>>(a);
        }
        if (C >= 128) {
            // QT[h] = (cx @ Wq[h]^T)^T — z=4, 1D remap
            mfma4<bf16, float, true><<<dim3(C / 128, 26, 4), 256, 0, stream>>>(
                cxall + cxoff[i], 0, 0, C, wqb, C2, 0, C, Qb, (long)C * NT, 0, NT,
                nullptr, (const float*)nullptr, NT, C, C, 3328, C, 0, 0,
                1.f, 0, nullptr);
            // S2[b][d][h*960+j] = scale * QT @ KT^T  (K=784 tail) — z=16, 1D
            mfma4<bf16, float, false><<<dim3(8, C / 128, 16), 256, 0, stream>>>(
                Qb, (long)C * NT, 784, NT, KT, 3010560, 784, NT,
                Sb, 960, (long)C * 3840, 3840,
                nullptr, (const float*)nullptr, C, 960, 784, C, 1024, 0, 0,
                scale, 0, statb);
        } else {
            mfma2<64, 64, bf16, float, true><<<dim3(1, 49, 4), 256, 0, stream>>>(
                cxall + cxoff[i], 0, 0, C, wqb, C2, 0, C, Qb, (long)C * NT, 0, NT,
                nullptr, (const float*)nullptr, NT, C, C, 1.f, 0, nullptr);
            mfma2<64, 64, bf16, float, false><<<dim3(15, 1, 16), 256, 0, stream>>>(
                Qb, (long)C * NT, 784, NT, KT, 3010560, 784, NT,
                Sb, 960, (long)C * 3840, 3840,
                nullptr, (const float*)nullptr, C, 960, 784, scale, 0, statb);
        }
        softmax_kernel<<<16 * C, 256, 0, stream>>>(Sb, statb, C);
        // tmp[h] = V-slab @ S[z]^T  (per-head K=960) -> ctx_sum — z=16, 1D
        if (C >= 128)
            mfma4<bf16, float, false><<<dim3(C / 128, 7, 16), 256, 0, stream>>>(
                Vb2, 960, 784L * 3840, 3840, Sb, 960, (long)C * 3840, 3840,
                Qb, (long)NT * C, 784L * C, C,
                nullptr, (const float*)nullptr, 784, C, 960, 896, C, 0, 0,
                1.f, 0, nullptr);
        else
            mfma2<64, 64, bf16, float, false><<<dim3(1, 13, 16), 256, 0, stream>>>(
                Vb2, 960, 784L * 3840, 3840, Sb, 960, (long)C * 3840, 3840,
                Qb, (long)NT * C, 784L * C, C,
                nullptr, (const float*)nullptr, 784, C, 960, 1.f, 0, nullptr);
        ctx_sum_kernel<<<(int)(((long)NT * C) / 1024), 256, 0, stream>>>(
            Qb, cxb, (long)NT * C);
        // x = emb + ctx @ Wo^T  -> bf16
        if (C == 512)
            mfma4<bf16, float, false><<<dim3(4, 26, 1), 256, 0, stream>>>(
                cxb, 0, 0, C, wob, 0, 0, C, xb, 0, 0, C,
                nullptr, emb[i], NT, C, C, 3328, C, 1, 13, 1.f, 0, nullptr);
        else if (C >= 128)
            mfma4<bf16, float, false><<<dim3(C / 128, 26, 1), 256, 0, stream>>>(
                cxb, 0, 0, C, wob, 0, 0, C, xb, 0, 0, C,
                nullptr, emb[i], NT, C, C, 3328, C, 0, 0, 1.f, 0, nullptr);
        else
            mfma2<64, 64, bf16, float, false><<<dim3(1, 49, 1), 256, 0, stream>>>(
                cxb, 0, 0, C, wob, 0, 0, C, xb, 0, 0, C,
                nullptr, emb[i], NT, C, C, 1.f, 0, nullptr);
        ln_rows_kernel<<<NT, 256, 0, stream>>>(xb, fng[i], fnb[i], cxb, C);
        // hid = gelu(lnx @ w1^T + b1) -> bf16
        if (C == 512)
            mfma4<bf16, float, false><<<dim3(16, 26, 1), 256, 0, stream>>>(
                cxb, 0, 0, C, w1b, 0, 0, C, Qb, 0, 0, 4 * C,
                b1[i], (const float*)nullptr, NT, 4 * C, C, 3328, 4 * C, 4, 13,
                1.f, 1, nullptr);
        else if (C == 256)
            mfma4<bf16, float, false><<<dim3(8, 26, 1), 256, 0, stream>>>(
                cxb, 0, 0, C, w1b, 0, 0, C, Qb, 0, 0, 4 * C,
                b1[i], (const float*)nullptr, NT, 4 * C, C, 3328, 4 * C, 2, 13,
                1.f, 1, nullptr);
        else if (C == 128)
            mfma4<bf16, float, false><<<dim3(4, 26, 1), 256, 0, stream>>>(
                cxb, 0, 0, C, w1b, 0, 0, C, Qb, 0, 0, 4 * C,
                b1[i], (const float*)nullptr, NT, 4 * C, C, 3328, 4 * C, 1, 13,
                1.f, 1, nullptr);
        else
            mfma2<64, 64, bf16, float, false><<<dim3(4, 49, 1), 256, 0, stream>>>(
                cxb, 0, 0, C, w1b, 0, 0, C, Qb, 0, 0, 4 * C,
                b1[i], (const float*)nullptr, NT, 4 * C, C, 1.f, 1, nullptr);
        // out = x + hid @ w2^T + b2  (fp32 store to d_out)
        if (C == 512)
            mfma4<float, bf16, false><<<dim3(4, 26, 1), 256, 0, stream>>>(
                Qb, 0, 0, 4 * C, w2b, 0, 0, 4 * C, out + ooff[i], 0, 0, C,
                b2[i], xb, NT, C, 4 * C, 3328, C, 1, 13, 1.f, 0, nullptr);
        else if (C >= 128)
            mfma4<float, bf16, false><<<dim3(C / 128, 26, 1), 256, 0, stream>>>(
                Qb, 0, 0, 4 * C, w2b, 0, 0, 4 * C, out + ooff[i], 0, 0, C,
                b2[i], xb, NT, C, 4 * C, 3328, C, 0, 0, 1.f, 0, nullptr);
        else
            mfma2<64, 64, float, bf16, false><<<dim3(1, 49, 1), 256, 0, stream>>>(
                Qb, 0, 0, 4 * C, w2b, 0, 0, 4 * C, out + ooff[i], 0, 0, C,
                b2[i], xb, NT, C, 4 * C, 1.f, 0, nullptr);
    }
}

// Round 8
// 740.462 us; speedup vs baseline: 1.2382x; 1.2382x over previous
//
#include <hip/hip_runtime.h>
#include <hip/hip_bf16.h>

// Block_ViT on MI355X — round 20: dispatch-granularity round.
// R19 post-mortem: 2D-XCD halved FETCH (62.8->27MB) but dur unchanged ->
// kernels latency-bound at ~350TF; the wall-vs-kernel-time gap (~250us) is
// dispatch ramp/drain across 44 launches. This round:
// (a) ONE up-front cvt of ALL weights (Wk,Wv + 4x13C^2 pool) + stat zeroing.
// (b) FFN phase grouped: Wo-all, ln_rows-all, FFN1-all, FFN2-all = 4 grouped
//     dispatches (208/780 blocks) replacing 16 small ones. mfma4g = mfma4
//     with descriptor decode and NO slow paths (all shapes fast-path clean).
// (c) ws re-laid with liveness overlap (hid<->KT, xb/cx3<->Vb2, ea<->Sb,
//     wk/wv<->QTtmp/Sb): 97.8MB < 102MB.
// Attention per branch unchanged from R19 (mfma4 BK=32 3-slot; mfma2 @C=64).
// B=4, N=784, H=4, Cs={64,128,256,512}, KV=960, NT=3136. fp32 in/out.

using bf16 = __hip_bfloat16;
typedef __attribute__((ext_vector_type(8))) short short8;   // 8 bf16 (4 VGPRs)
typedef __attribute__((ext_vector_type(4))) float f32x4;    // MFMA acc

__device__ inline float bf2f(unsigned short u) {
    return __uint_as_float(((unsigned int)u) << 16);
}
__device__ inline unsigned short f2b(float f) {            // RTNE fp32->bf16
    unsigned int u = __float_as_uint(f);
    return (unsigned short)((u + 0x7fffu + ((u >> 16) & 1u)) >> 16);
}
__device__ inline float ld1f(const float* p) { return *p; }
__device__ inline float ld1f(const bf16* p) { return bf2f(*(const unsigned short*)p); }
__device__ inline void st1(float* p, float v) { *p = v; }
__device__ inline void st1(bf16* p, float v) { *((unsigned short*)p) = f2b(v); }
__device__ inline float4 ld4f(const bf16* p) {
    ushort4 u = *(const ushort4*)p;
    return make_float4(bf2f(u.x), bf2f(u.y), bf2f(u.z), bf2f(u.w));
}

// async global->LDS, 16 B per lane; LDS dest = wave-uniform base + lane*16
__device__ __forceinline__ void cp16(const void* g, void* l) {
    __builtin_amdgcn_global_load_lds(
        (const __attribute__((address_space(1))) void*)g,
        (__attribute__((address_space(3))) void*)l, 16, 0, 0);
}

// ---- block reductions (256 threads = 4 waves) ----
__device__ inline float blockSum256(float v, float* red) {
    #pragma unroll
    for (int o = 32; o > 0; o >>= 1) v += __shfl_down(v, o);
    int t = threadIdx.x;
    if ((t & 63) == 0) red[t >> 6] = v;
    __syncthreads();
    float r = red[0] + red[1] + red[2] + red[3];
    __syncthreads();
    return r;
}
__device__ inline float blockMax256(float v, float* red) {
    #pragma unroll
    for (int o = 32; o > 0; o >>= 1) v = fmaxf(v, __shfl_down(v, o));
    int t = threadIdx.x;
    if ((t & 63) == 0) red[t >> 6] = v;
    __syncthreads();
    float r = fmaxf(fmaxf(red[0], red[1]), fmaxf(red[2], red[3]));
    __syncthreads();
    return r;
}

// ---- fp32 -> bf16 conversion of ALL weights (18 segments) + stat zeroing ----
struct CvtN {
    const float* s[18];
    unsigned short* d[18];
    long n[18];
    float* z;             // zero 128 floats (4 branches x 32 IN stats)
};
__global__ __launch_bounds__(256)
void cvtn_kernel(CvtN a) {
    if (a.z && blockIdx.x == 0 && threadIdx.x < 128) a.z[threadIdx.x] = 0.f;
    long tid = (long)blockIdx.x * 256 + threadIdx.x;
    long stride = (long)gridDim.x * 256;
    for (int g = 0; g < 18; g++) {
        const float* s = a.s[g];
        unsigned short* d = a.d[g];
        long n = a.n[g];
        for (long i = tid * 4; i < n; i += stride * 4) {
            float4 v = *(const float4*)(s + i);
            *(ushort4*)(d + i) = make_ushort4(f2b(v.x), f2b(v.y), f2b(v.z), f2b(v.w));
        }
    }
}

// ==== mfma4: 128x128, 4 waves (2x2), BK=32, 3 LDS slots (R19, unchanged) ====
template <class CT, class RT, bool TO>
__global__ __launch_bounds__(256, 3)
void mfma4(const bf16* __restrict__ A, long Ah, long Ab, int lda,
           const bf16* __restrict__ B, long Bh, long Bb, int ldb,
           CT* __restrict__ Cp, long Ch, long Cb, int ldc,
           const float* __restrict__ bias, const RT* __restrict__ res,
           int M, int N, int K, int Mpad, int Npad, int qx, int hy,
           float alpha, int dogelu, float* __restrict__ stat) {
    __shared__ short Asl[3][128][32];
    __shared__ short Bsl[3][128][32];
    int gx = gridDim.x, gy = gridDim.y;
    int orig = ((int)blockIdx.z * gy + (int)blockIdx.y) * gx + (int)blockIdx.x;
    int bx, by, bz;
    if (qx) {                       // 2D: grid (4*qx, 2*hy, 1), nwg%8==0
        int c = orig & 7, r2 = orig >> 3;
        bx = (c & 3) * qx + r2 % qx;
        by = (c >> 2) * hy + r2 / qx;
        bz = 0;
    } else {                        // 1D m204 bijective
        int nxy = gx * gy, nwg = nxy * (int)gridDim.z;
        int q = nwg >> 3, r8 = nwg & 7;
        int xcd = orig & 7, pos = orig >> 3;
        int wgid = (xcd < r8 ? xcd * (q + 1) : r8 * (q + 1) + (xcd - r8) * q) + pos;
        bz = wgid / nxy;
        int rem = wgid - bz * nxy;
        by = rem / gx; bx = rem - by * gx;
    }
    int z = bz;
    A += (long)(z & 3) * Ah + (long)(z >> 2) * Ab;
    B += (long)(z & 3) * Bh + (long)(z >> 2) * Bb;
    Cp += (long)(z & 3) * Ch + (long)(z >> 2) * Cb;
    int m0 = by * 128, n0 = bx * 128;
    int t = threadIdx.x, lane = t & 63, wv = t >> 6;
    int col = lane & 15, quad = lane >> 4;
    int wm = wv >> 1, wn = wv & 1;
    f32x4 acc[4][4];
    #pragma unroll
    for (int i = 0; i < 4; i++)
        #pragma unroll
        for (int j = 0; j < 4; j++) acc[i][j] = (f32x4){0.f, 0.f, 0.f, 0.f};

    const bool fA = (m0 + 128 <= Mpad);
    const bool fB = (n0 + 128 <= Npad);
    int srow = lane >> 2;
    int scol = ((lane & 3) ^ ((lane >> 3) & 3)) << 3;
    int rslot = (quad ^ ((col >> 1) & 3)) << 3;

    auto stageA = [&](int s3, int kt) {
        int k0 = kt * 32;
        if (fA && k0 + 32 <= K) {
            #pragma unroll
            for (int r = 0; r < 2; r++) {
                int R0 = (r * 4 + wv) * 16;
                cp16(A + (long)(m0 + R0 + srow) * lda + k0 + scol, &Asl[s3][R0][0]);
            }
        } else {
            #pragma unroll
            for (int r = 0; r < 2; r++) {
                int idx = r * 256 + t;
                int row = idx >> 2, sl = idx & 3;
                int f2 = (row >> 1) & 3;
                short8 v = {};
                if (m0 + row < M && k0 + sl * 8 < K)
                    v = *(const short8*)(A + (long)(m0 + row) * lda + k0 + sl * 8);
                *(short8*)&Asl[s3][row][(sl ^ f2) * 8] = v;
            }
            asm volatile("s_waitcnt lgkmcnt(0)" ::: "memory");
        }
    };
    auto stageB = [&](int s3, int kt) {
        int k0 = kt * 32;
        if (fB && k0 + 32 <= K) {
            #pragma unroll
            for (int r = 0; r < 2; r++) {
                int R0 = (r * 4 + wv) * 16;
                cp16(B + (long)(n0 + R0 + srow) * ldb + k0 + scol, &Bsl[s3][R0][0]);
            }
        } else {
            #pragma unroll
            for (int r = 0; r < 2; r++) {
                int idx = r * 256 + t;
                int row = idx >> 2, sl = idx & 3;
                int f2 = (row >> 1) & 3;
                short8 v = {};
                if (n0 + row < N && k0 + sl * 8 < K)
                    v = *(const short8*)(B + (long)(n0 + row) * ldb + k0 + sl * 8);
                *(short8*)&Bsl[s3][row][(sl ^ f2) * 8] = v;
            }
            asm volatile("s_waitcnt lgkmcnt(0)" ::: "memory");
        }
    };

    int nk = (K + 31) >> 5;
    stageA(0, 0); stageB(0, 0);
    stageA(1, 1); stageB(1, 1);
    __syncthreads();

    for (int kt = 0; kt < nk; kt++) {
        int cur = kt % 3;
        short8 af[4], bf4[4];
        #pragma unroll
        for (int mi = 0; mi < 4; mi++)
            af[mi] = *(const short8*)&Asl[cur][wm * 64 + mi * 16 + col][rslot];
        #pragma unroll
        for (int ni = 0; ni < 4; ni++)
            bf4[ni] = *(const short8*)&Bsl[cur][wn * 64 + ni * 16 + col][rslot];
        int pend = 0;
        if (kt + 2 < nk) {
            int s3 = (kt + 2) % 3;
            stageA(s3, kt + 2); stageB(s3, kt + 2);
            if ((kt + 2) * 32 + 32 <= K) pend = (fA ? 2 : 0) + (fB ? 2 : 0);
        }
        __builtin_amdgcn_s_barrier();
        asm volatile("s_waitcnt lgkmcnt(0)" ::: "memory");
        __builtin_amdgcn_sched_barrier(0);
        __builtin_amdgcn_s_setprio(1);
        #pragma unroll
        for (int mi = 0; mi < 4; mi++)
            #pragma unroll
            for (int ni = 0; ni < 4; ni++)
                acc[mi][ni] = __builtin_amdgcn_mfma_f32_16x16x32_bf16(
                    af[mi], bf4[ni], acc[mi][ni], 0, 0, 0);
        __builtin_amdgcn_s_setprio(0);
        if (kt + 1 < nk) {
            if (pend == 4)      asm volatile("s_waitcnt vmcnt(4)" ::: "memory");
            else if (pend == 2) asm volatile("s_waitcnt vmcnt(2)" ::: "memory");
            else                asm volatile("s_waitcnt vmcnt(0)" ::: "memory");
            __builtin_amdgcn_s_barrier();
        }
    }
    float psum = 0.f, psq = 0.f;
    #pragma unroll
    for (int mi = 0; mi < 4; mi++) {
        int gmB = m0 + wm * 64 + mi * 16 + quad * 4;
        #pragma unroll
        for (int ni = 0; ni < 4; ni++) {
            int gn = n0 + wn * 64 + ni * 16 + col;
            if constexpr (TO) {
                if (gmB < M && gn < N) {
                    ushort4 w = make_ushort4(f2b(acc[mi][ni][0] * alpha),
                                             f2b(acc[mi][ni][1] * alpha),
                                             f2b(acc[mi][ni][2] * alpha),
                                             f2b(acc[mi][ni][3] * alpha));
                    *(ushort4*)((unsigned short*)Cp + (long)gn * ldc + gmB) = w;
                }
            } else {
                if (gn < N) {
                    float bz2 = bias ? bias[gn] : 0.f;
                    #pragma unroll
                    for (int r = 0; r < 4; r++) {
                        int gm = gmB + r;
                        if (gm < M) {
                            float v = acc[mi][ni][r] * alpha + bz2;
                            if (dogelu) v = 0.5f * v * (1.f + erff(v * 0.70710678118f));
                            if (res) v += ld1f(res + (long)gm * ldc + gn);
                            st1(Cp + (long)gm * ldc + gn, v);
                            psum += v; psq += v * v;
                        }
                    }
                }
            }
        }
    }
    if (stat) {
        __syncthreads();
        #pragma unroll
        for (int o = 32; o > 0; o >>= 1) {
            psum += __shfl_down(psum, o);
            psq  += __shfl_down(psq, o);
        }
        float* red = (float*)Asl;
        if ((t & 63) == 0) { red[wv] = psum; red[4 + wv] = psq; }
        __syncthreads();
        if (t == 0) {
            atomicAdd(&stat[2 * z],     red[0] + red[1] + red[2] + red[3]);
            atomicAdd(&stat[2 * z + 1], red[4] + red[5] + red[6] + red[7]);
        }
    }
}

// ==== mfma4g: grouped (4-problem) 128x128 GEMM, pure fast path ====
// All groups MUST have: M rows readable to 3328, B rows readable to nbx*128,
// K % 32 == 0, K >= 64. Decode: 1D m204 remap -> group by cum[] -> (by,bx).
struct G4 {
    const bf16* A[4]; const bf16* B[4]; void* Cv[4];
    const float* bias[4]; const void* res[4];
    int M[4], N[4], K[4], lda[4], ldb[4], ldc[4], nbx[4];
    int cum[5];
};
template <class CT, class RT>
__global__ __launch_bounds__(256, 3)
void mfma4g(G4 gp, int dogelu) {
    __shared__ short Asl[3][128][32];
    __shared__ short Bsl[3][128][32];
    int nwg = gridDim.x;
    int orig = blockIdx.x;
    int q = nwg >> 3, r8 = nwg & 7;
    int xcd = orig & 7, pos = orig >> 3;
    int wgid = (xcd < r8 ? xcd * (q + 1) : r8 * (q + 1) + (xcd - r8) * q) + pos;
    int gi = 0;
    if (wgid >= gp.cum[1]) gi = 1;
    if (wgid >= gp.cum[2]) gi = 2;
    if (wgid >= gp.cum[3]) gi = 3;
    int local = wgid - gp.cum[gi];
    int nbx = gp.nbx[gi];
    int by = local / nbx, bx = local - by * nbx;
    const bf16* A = gp.A[gi];
    const bf16* B = gp.B[gi];
    CT* Cp = (CT*)gp.Cv[gi];
    const float* bias = gp.bias[gi];
    const RT* res = (const RT*)gp.res[gi];
    int M = gp.M[gi], N = gp.N[gi], K = gp.K[gi];
    int lda = gp.lda[gi], ldb = gp.ldb[gi], ldc = gp.ldc[gi];
    int m0 = by * 128, n0 = bx * 128;
    int t = threadIdx.x, lane = t & 63, wv = t >> 6;
    int col = lane & 15, quad = lane >> 4;
    int wm = wv >> 1, wn = wv & 1;
    f32x4 acc[4][4];
    #pragma unroll
    for (int i = 0; i < 4; i++)
        #pragma unroll
        for (int j = 0; j < 4; j++) acc[i][j] = (f32x4){0.f, 0.f, 0.f, 0.f};

    int srow = lane >> 2;
    int scol = ((lane & 3) ^ ((lane >> 3) & 3)) << 3;
    int rslot = (quad ^ ((col >> 1) & 3)) << 3;

    auto stageA = [&](int s3, int kt) {
        int k0 = kt * 32;
        #pragma unroll
        for (int r = 0; r < 2; r++) {
            int R0 = (r * 4 + wv) * 16;
            cp16(A + (long)(m0 + R0 + srow) * lda + k0 + scol, &Asl[s3][R0][0]);
        }
    };
    auto stageB = [&](int s3, int kt) {
        int k0 = kt * 32;
        #pragma unroll
        for (int r = 0; r < 2; r++) {
            int R0 = (r * 4 + wv) * 16;
            cp16(B + (long)(n0 + R0 + srow) * ldb + k0 + scol, &Bsl[s3][R0][0]);
        }
    };

    int nk = K >> 5;                 // K % 32 == 0 by construction
    stageA(0, 0); stageB(0, 0);
    stageA(1, 1); stageB(1, 1);
    __syncthreads();

    for (int kt = 0; kt < nk; kt++) {
        int cur = kt % 3;
        short8 af[4], bf4[4];
        #pragma unroll
        for (int mi = 0; mi < 4; mi++)
            af[mi] = *(const short8*)&Asl[cur][wm * 64 + mi * 16 + col][rslot];
        #pragma unroll
        for (int ni = 0; ni < 4; ni++)
            bf4[ni] = *(const short8*)&Bsl[cur][wn * 64 + ni * 16 + col][rslot];
        bool st = (kt + 2 < nk);
        if (st) {
            int s3 = (kt + 2) % 3;
            stageA(s3, kt + 2); stageB(s3, kt + 2);
        }
        __builtin_amdgcn_s_barrier();
        asm volatile("s_waitcnt lgkmcnt(0)" ::: "memory");
        __builtin_amdgcn_sched_barrier(0);
        __builtin_amdgcn_s_setprio(1);
        #pragma unroll
        for (int mi = 0; mi < 4; mi++)
            #pragma unroll
            for (int ni = 0; ni < 4; ni++)
                acc[mi][ni] = __builtin_amdgcn_mfma_f32_16x16x32_bf16(
                    af[mi], bf4[ni], acc[mi][ni], 0, 0, 0);
        __builtin_amdgcn_s_setprio(0);
        if (kt + 1 < nk) {
            if (st) asm volatile("s_waitcnt vmcnt(4)" ::: "memory");
            else    asm volatile("s_waitcnt vmcnt(0)" ::: "memory");
            __builtin_amdgcn_s_barrier();
        }
    }
    #pragma unroll
    for (int mi = 0; mi < 4; mi++) {
        int gmB = m0 + wm * 64 + mi * 16 + quad * 4;
        #pragma unroll
        for (int ni = 0; ni < 4; ni++) {
            int gn = n0 + wn * 64 + ni * 16 + col;
            if (gn < N) {
                float bz2 = bias ? bias[gn] : 0.f;
                #pragma unroll
                for (int r = 0; r < 4; r++) {
                    int gm = gmB + r;
                    if (gm < M) {
                        float v = acc[mi][ni][r] + bz2;
                        if (dogelu) v = 0.5f * v * (1.f + erff(v * 0.70710678118f));
                        if (res) v += ld1f(res + (long)gm * ldc + gn);
                        st1(Cp + (long)gm * ldc + gn, v);
                    }
                }
            }
        }
    }
}

// ==== mfma2 (R13 form) + optional fused stats — C=64 attention only ====
template <int TM, int TN, class CT, class RT, bool TO>
__global__ __launch_bounds__(256)
void mfma2(const bf16* __restrict__ A, long Ah, long Ab, int lda,
           const bf16* __restrict__ B, long Bh, long Bb, int ldb,
           CT* __restrict__ Cp, long Ch, long Cb, int ldc,
           const float* __restrict__ bias, const RT* __restrict__ res,
           int M, int N, int K, float alpha, int dogelu,
           float* __restrict__ stat) {
    constexpr int MI = TM / 32, NI = TN / 32;
    __shared__ short As[2][TM * 32];
    __shared__ short Bs[2][TN * 32];
    int z = blockIdx.z;
    A += (long)(z & 3) * Ah + (long)(z >> 2) * Ab;
    B += (long)(z & 3) * Bh + (long)(z >> 2) * Bb;
    Cp += (long)(z & 3) * Ch + (long)(z >> 2) * Cb;
    int m0 = blockIdx.y * TM, n0 = blockIdx.x * TN;
    int t = threadIdx.x, lane = t & 63, wv = t >> 6;
    int col = lane & 15, quad = lane >> 4;
    int wm = wv >> 1, wn = wv & 1;
    f32x4 acc[MI][NI];
    #pragma unroll
    for (int i = 0; i < MI; i++)
        #pragma unroll
        for (int j = 0; j < NI; j++) acc[i][j] = (f32x4){0.f, 0.f, 0.f, 0.f};

    const bool fastblk = (m0 + TM <= M) && (n0 + TN <= N);
    int lrow = lane >> 2;
    int lcol = ((lane & 3) ^ ((lane >> 3) & 3)) << 3;
    int sr = t >> 2;
    int swz = ((t & 3) ^ ((t >> 3) & 3)) << 3;
    int sdst = (t & 3) << 3;
    int rdslot = (quad ^ ((col >> 1) & 3)) << 3;

    auto stage = [&](int b, int k0) {
        if (fastblk && (k0 + 32 <= K)) {
            #pragma unroll
            for (int u = 0; u < TM / 64; u++) {
                int c = wv + 4 * u;
                int r = c * 16 + lrow;
                cp16(A + (long)(m0 + r) * lda + k0 + lcol, &As[b][c * 512]);
            }
            #pragma unroll
            for (int u = 0; u < TN / 64; u++) {
                int c = wv + 4 * u;
                int r = c * 16 + lrow;
                cp16(B + (long)(n0 + r) * ldb + k0 + lcol, &Bs[b][c * 512]);
            }
        } else {
            #pragma unroll
            for (int u = 0; u < TM / 64; u++) {
                int r = sr + u * 64;
                float4 v = make_float4(0.f, 0.f, 0.f, 0.f);
                if (m0 + r < M && k0 + swz < K)
                    v = *(const float4*)(A + (long)(m0 + r) * lda + k0 + swz);
                *(float4*)&As[b][r * 32 + sdst] = v;
            }
            #pragma unroll
            for (int u = 0; u < TN / 64; u++) {
                int r = sr + u * 64;
                float4 v = make_float4(0.f, 0.f, 0.f, 0.f);
                if (n0 + r < N && k0 + swz < K)
                    v = *(const float4*)(B + (long)(n0 + r) * ldb + k0 + swz);
                *(float4*)&Bs[b][r * 32 + sdst] = v;
            }
        }
    };

    int nk = (K + 31) >> 5;
    stage(0, 0);
    __syncthreads();
    int cur = 0;
    for (int s = 0; s < nk; s++) {
        if (s + 1 < nk) stage(cur ^ 1, (s + 1) * 32);
        short8 af[MI], bfr[NI];
        #pragma unroll
        for (int mi = 0; mi < MI; mi++)
            af[mi] = *(const short8*)&As[cur][(wm * (TM / 2) + mi * 16 + col) * 32 + rdslot];
        #pragma unroll
        for (int ni = 0; ni < NI; ni++)
            bfr[ni] = *(const short8*)&Bs[cur][(wn * (TN / 2) + ni * 16 + col) * 32 + rdslot];
        #pragma unroll
        for (int mi = 0; mi < MI; mi++)
            #pragma unroll
            for (int ni = 0; ni < NI; ni++)
                acc[mi][ni] = __builtin_amdgcn_mfma_f32_16x16x32_bf16(
                    af[mi], bfr[ni], acc[mi][ni], 0, 0, 0);
        if (s + 1 < nk) __syncthreads();
        cur ^= 1;
    }
    float psum = 0.f, psq = 0.f;
    #pragma unroll
    for (int mi = 0; mi < MI; mi++) {
        int gmB = m0 + wm * (TM / 2) + mi * 16 + quad * 4;
        #pragma unroll
        for (int ni = 0; ni < NI; ni++) {
            int gn = n0 + wn * (TN / 2) + ni * 16 + col;
            if constexpr (TO) {
                if (gmB < M && gn < N) {
                    ushort4 w = make_ushort4(f2b(acc[mi][ni][0] * alpha),
                                             f2b(acc[mi][ni][1] * alpha),
                                             f2b(acc[mi][ni][2] * alpha),
                                             f2b(acc[mi][ni][3] * alpha));
                    *(ushort4*)((unsigned short*)Cp + (long)gn * ldc + gmB) = w;
                }
            } else {
                if (gn < N) {
                    float bz = bias ? bias[gn] : 0.f;
                    #pragma unroll
                    for (int r = 0; r < 4; r++) {
                        int gm = gmB + r;
                        if (gm < M) {
                            float v = acc[mi][ni][r] * alpha + bz;
                            if (dogelu) v = 0.5f * v * (1.f + erff(v * 0.70710678118f));
                            if (res) v += ld1f(res + (long)gm * ldc + gn);
                            st1(Cp + (long)gm * ldc + gn, v);
                            psum += v; psq += v * v;
                        }
                    }
                }
            }
        }
    }
    if (stat) {
        __syncthreads();
        #pragma unroll
        for (int o = 32; o > 0; o >>= 1) {
            psum += __shfl_down(psum, o);
            psq  += __shfl_down(psq, o);
        }
        float* red = (float*)As;
        if ((t & 63) == 0) { red[wv] = psum; red[4 + wv] = psq; }
        __syncthreads();
        if (t == 0) {
            atomicAdd(&stat[2 * z],     red[0] + red[1] + red[2] + red[3]);
            atomicAdd(&stat[2 * z + 1], red[4] + red[5] + red[6] + red[7]);
        }
    }
}

// ---- merged LayerNorms: concat-LN (ea) + 4 branch first-LNs ----
struct LNA {
    const float* e[4];
    const float* ag[4];
    const float* ab[4];
    const float* cg;
    const float* cbb;
    bf16* y[4];
    bf16* ea;
};
__global__ __launch_bounds__(256)
void ln_all_kernel(LNA a) {
    __shared__ float x[960];
    __shared__ float red[4];
    long row = blockIdx.x;
    int t = threadIdx.x;
    const int off[5] = {0, 64, 192, 448, 960};
    {
        const float* p1 = a.e[0] + row * 64;
        const float* p2 = a.e[1] + row * 128;
        const float* p3 = a.e[2] + row * 256;
        const float* p4 = a.e[3] + row * 512;
        if (t < 64) x[t] = p1[t];
        for (int i = t; i < 128; i += 256) x[64 + i]  = p2[i];
        for (int i = t; i < 256; i += 256) x[192 + i] = p3[i];
        for (int i = t; i < 512; i += 256) x[448 + i] = p4[i];
    }
    __syncthreads();
    float ssum[4], ssq[4];
    #pragma unroll
    for (int br = 0; br < 4; br++) {
        float s = 0.f, q = 0.f;
        for (int i = off[br] + t; i < off[br + 1]; i += 256) {
            float v = x[i]; s += v; q += v * v;
        }
        ssum[br] = blockSum256(s, red);
        ssq[br]  = blockSum256(q, red);
    }
    float S1 = ssum[0] + ssum[1] + ssum[2] + ssum[3];
    float S2 = ssq[0] + ssq[1] + ssq[2] + ssq[3];
    float muA = S1 * (1.f / 960.f);
    float rA = rsqrtf(S2 * (1.f / 960.f) - muA * muA + 1e-6f);
    for (int i = t; i < 960; i += 256)
        st1(a.ea + row * 960 + i, (x[i] - muA) * rA * a.cg[i] + a.cbb[i]);
    #pragma unroll
    for (int br = 0; br < 4; br++) {
        int C = off[br + 1] - off[br];
        float mu = ssum[br] / C;
        float rr = rsqrtf(ssq[br] / C - mu * mu + 1e-6f);
        const float* g = a.ag[br];
        const float* b = a.ab[br];
        bf16* y = a.y[br] + row * C;
        for (int i = t; i < C; i += 256)
            st1(y + i, (x[off[br] + i] - mu) * rr * g[i] + b[i]);
    }
}

// ---- grouped row LayerNorm: grid (3136, 4) ----
struct LR4 {
    const bf16* X[4];
    const float* g[4];
    const float* b[4];
    bf16* Y[4];
    int C[4];
};
__global__ __launch_bounds__(256)
void ln_rows4_kernel(LR4 a) {
    __shared__ float x[512];
    __shared__ float red[4];
    int br = blockIdx.y;
    long row = blockIdx.x;
    int C = a.C[br];
    int t = threadIdx.x;
    const bf16* xr = a.X[br] + row * C;
    float s = 0.f, q = 0.f;
    for (int i = t; i < C; i += 256) { float v = ld1f(xr + i); x[i] = v; s += v; q += v * v; }
    float S1 = blockSum256(s, red), S2 = blockSum256(q, red);
    float mu = S1 / C;
    float r = rsqrtf(S2 / C - mu * mu + 1e-6f);
    const float* g = a.g[br];
    const float* b = a.b[br];
    bf16* y = a.Y[br] + row * C;
    for (int i = t; i < C; i += 256)
        st1(y + i, (x[i] - mu) * r * g[i] + b[i]);
}

// ---- ctx head-sum: ctx[i] = 0.25*sum_h tmp[h][i] ----
__global__ __launch_bounds__(256)
void ctx_sum_kernel(const bf16* __restrict__ tmp, bf16* __restrict__ ctx, long NTC) {
    long i = ((long)blockIdx.x * 256 + threadIdx.x) * 4;
    float4 a = ld4f(tmp + i);
    float4 b = ld4f(tmp + NTC + i);
    float4 c = ld4f(tmp + 2 * NTC + i);
    float4 d = ld4f(tmp + 3 * NTC + i);
    ushort4 o = make_ushort4(f2b((a.x + b.x + c.x + d.x) * 0.25f),
                             f2b((a.y + b.y + c.y + d.y) * 0.25f),
                             f2b((a.z + b.z + c.z + d.z) * 0.25f),
                             f2b((a.w + b.w + c.w + d.w) * 0.25f));
    *(ushort4*)(ctx + i) = o;
}

// ---- softmax over last dim (960) of S[b][C][3840]; rstd from fused stats ----
__global__ __launch_bounds__(256)
void softmax_kernel(bf16* __restrict__ S, const float* __restrict__ stat, int C) {
    __shared__ float x[960];
    __shared__ float red[4];
    long r = blockIdx.x;
    int t = threadIdx.x;
    int z = (int)(r / C);           // stats z: z&3=h, z>>2=b (matches S-GEMM)
    int d = (int)(r % C);
    float n = 960.f * (float)C;
    float s0 = stat[2 * z], q0 = stat[2 * z + 1];
    float mu = s0 / n;
    float rs = rsqrtf(q0 / n - mu * mu + 1e-5f);
    int h = z & 3, b = z >> 2;
    bf16* row = S + (long)b * C * 3840 + (long)d * 3840 + h * 960;
    float mx = -3.4e38f;
    for (int i = t; i < 960; i += 256) {
        float v = ld1f(row + i) * rs; x[i] = v; mx = fmaxf(mx, v);
    }
    float M = blockMax256(mx, red);
    float s = 0.f;
    for (int i = t; i < 960; i += 256) { float e = __expf(x[i] - M); x[i] = e; s += e; }
    float Ssum = blockSum256(s, red);
    float inv = 1.f / Ssum;
    for (int i = t; i < 960; i += 256) st1(row + i, x[i] * inv);
}

extern "C" void kernel_launch(void* const* d_in, const int* in_sizes, int n_in,
                              void* d_out, int out_size, void* d_ws, size_t ws_size,
                              hipStream_t stream) {
    (void)in_sizes; (void)n_in; (void)out_size; (void)ws_size;
    const int Cs[4] = {64, 128, 256, 512};
    const float *emb[4], *ang[4], *anb[4], *Wq[4], *Wo[4], *fng[4], *fnb[4], *w1[4], *b1[4], *w2[4], *b2[4];
    for (int i = 0; i < 4; i++) {
        const int base = i * 11;
        emb[i] = (const float*)d_in[base + 0];
        ang[i] = (const float*)d_in[base + 1];
        anb[i] = (const float*)d_in[base + 2];
        Wq[i]  = (const float*)d_in[base + 3];
        Wo[i]  = (const float*)d_in[base + 4];
        fng[i] = (const float*)d_in[base + 5];
        fnb[i] = (const float*)d_in[base + 6];
        w1[i]  = (const float*)d_in[base + 7];
        b1[i]  = (const float*)d_in[base + 8];
        w2[i]  = (const float*)d_in[base + 9];
        b2[i]  = (const float*)d_in[base + 10];
    }
    const float* anAg = (const float*)d_in[44];
    const float* anAb = (const float*)d_in[45];
    const float* Wk   = (const float*)d_in[46];
    const float* Wv   = (const float*)d_in[47];

    const int NT = 3136;
    char* wsb = (char*)d_ws;
    // ---- layout (bytes), end 97,838,080 < 102 MB; liveness overlaps noted ----
    unsigned short* wp = (unsigned short*)(wsb);          // weights pool 9,052,160
    float* statb = (float*)(wsb + 9052160);               // 128 floats
    bf16*  KT    = (bf16*)(wsb + 9053184);                // [3840][3136] 24.08MB
    bf16*  hid   = (bf16*)(wsb + 9053184);                // phase B (over KT)
    bf16*  Vb2   = (bf16*)(wsb + 33137664);               // [3136][3840] 24.08MB
    bf16*  xball = (bf16*)(wsb + 33137664);               // phase B (over Vb2)
    bf16*  cx3   = (bf16*)(wsb + 39158784);               // phase B (over Vb2)
    bf16*  QT    = (bf16*)(wsb + 57222144);               // QT/tmp pool 12.85MB
    bf16*  wkb   = (bf16*)(wsb + 57222144);               // early (over QT)
    bf16*  Sb    = (bf16*)(wsb + 70067200);               // S pool 15.73MB
    bf16*  ea    = (bf16*)(wsb + 70067200);               // early (over Sb)
    bf16*  wvb   = (bf16*)(wsb + 76088320);               // early (over Sb)
    bf16*  cxall = (bf16*)(wsb + 85795840);               // first-LN out 6.02MB
    bf16*  cx2   = (bf16*)(wsb + 91816960);               // ctx all branches 6.02MB

    const long wb[4] = {0, 53248, 266240, 1118208};       // 13*C^2 prefix (elems)
    const long co[4] = {0, 64L * NT, 192L * NT, 448L * NT}; // [NT][C] packed offs
    const long ho[4] = {0, 802816, 2408448, 5619712};     // hid offsets (elems)

    float* out = (float*)d_out;
    const long ooff[4] = {0, 200704, 602112, 1404928};
    const float scale = 0.03227486121f;  // 1/sqrt(960)

    // ---- 1) all weights -> bf16 + zero stats ----
    {
        CvtN a;
        a.s[0] = Wk; a.d[0] = (unsigned short*)wkb; a.n[0] = 3686400;
        a.s[1] = Wv; a.d[1] = (unsigned short*)wvb; a.n[1] = 3686400;
        for (int i = 0; i < 4; i++) {
            const long C2 = (long)Cs[i] * Cs[i];
            a.s[2 + 4 * i] = Wq[i]; a.d[2 + 4 * i] = wp + wb[i];          a.n[2 + 4 * i] = 4 * C2;
            a.s[3 + 4 * i] = Wo[i]; a.d[3 + 4 * i] = wp + wb[i] + 4 * C2; a.n[3 + 4 * i] = C2;
            a.s[4 + 4 * i] = w1[i]; a.d[4 + 4 * i] = wp + wb[i] + 5 * C2; a.n[4 + 4 * i] = 4 * C2;
            a.s[5 + 4 * i] = w2[i]; a.d[5 + 4 * i] = wp + wb[i] + 9 * C2; a.n[5 + 4 * i] = 4 * C2;
        }
        a.z = statb;
        cvtn_kernel<<<1024, 256, 0, stream>>>(a);
    }
    // ---- 2) merged LayerNorms ----
    {
        LNA a;
        for (int i = 0; i < 4; i++) {
            a.e[i] = emb[i]; a.ag[i] = ang[i]; a.ab[i] = anb[i];
            a.y[i] = cxall + co[i];
        }
        a.cg = anAg; a.cbb = anAb; a.ea = ea;
        ln_all_kernel<<<3136, 256, 0, stream>>>(a);
    }
    // ---- 3) K/V projections (2D XCD partition) ----
    mfma4<bf16, float, true><<<dim3(32, 26, 1), 256, 0, stream>>>(
        ea, 0, 0, 960, wkb, 0, 0, 960, KT, 0, 0, NT,
        nullptr, (const float*)nullptr, NT, 3840, 960, 3328, 4096, 8, 13,
        1.f, 0, nullptr);
    mfma4<bf16, float, false><<<dim3(32, 26, 1), 256, 0, stream>>>(
        ea, 0, 0, 960, wvb, 0, 0, 960, Vb2, 0, 0, 3840,
        nullptr, (const float*)nullptr, NT, 3840, 960, 3328, 4096, 8, 13,
        1.f, 0, nullptr);

    // ---- 4) per-branch attention ----
    for (int i = 0; i < 4; i++) {
        const int C = Cs[i];
        const long C2 = (long)C * C;
        bf16* wqb = (bf16*)(wp + wb[i]);
        float* st = statb + 32 * i;
        if (C >= 128) {
            mfma4<bf16, float, true><<<dim3(C / 128, 26, 4), 256, 0, stream>>>(
                cxall + co[i], 0, 0, C, wqb, C2, 0, C, QT, (long)C * NT, 0, NT,
                nullptr, (const float*)nullptr, NT, C, C, 3328, C, 0, 0,
                1.f, 0, nullptr);
            mfma4<bf16, float, false><<<dim3(8, C / 128, 16), 256, 0, stream>>>(
                QT, (long)C * NT, 784, NT, KT, 3010560, 784, NT,
                Sb, 960, (long)C * 3840, 3840,
                nullptr, (const float*)nullptr, C, 960, 784, C, 1024, 0, 0,
                scale, 0, st);
        } else {
            mfma2<64, 64, bf16, float, true><<<dim3(1, 49, 4), 256, 0, stream>>>(
                cxall + co[i], 0, 0, C, wqb, C2, 0, C, QT, (long)C * NT, 0, NT,
                nullptr, (const float*)nullptr, NT, C, C, 1.f, 0, nullptr);
            mfma2<64, 64, bf16, float, false><<<dim3(15, 1, 16), 256, 0, stream>>>(
                QT, (long)C * NT, 784, NT, KT, 3010560, 784, NT,
                Sb, 960, (long)C * 3840, 3840,
                nullptr, (const float*)nullptr, C, 960, 784, scale, 0, st);
        }
        softmax_kernel<<<16 * C, 256, 0, stream>>>(Sb, st, C);
        if (C >= 128)
            mfma4<bf16, float, false><<<dim3(C / 128, 7, 16), 256, 0, stream>>>(
                Vb2, 960, 784L * 3840, 3840, Sb, 960, (long)C * 3840, 3840,
                QT, (long)NT * C, 784L * C, C,
                nullptr, (const float*)nullptr, 784, C, 960, 896, C, 0, 0,
                1.f, 0, nullptr);
        else
            mfma2<64, 64, bf16, float, false><<<dim3(1, 13, 16), 256, 0, stream>>>(
                Vb2, 960, 784L * 3840, 3840, Sb, 960, (long)C * 3840, 3840,
                QT, (long)NT * C, 784L * C, C,
                nullptr, (const float*)nullptr, 784, C, 960, 1.f, 0, nullptr);
        ctx_sum_kernel<<<(int)(((long)NT * C) / 1024), 256, 0, stream>>>(
            QT, cx2 + co[i], (long)NT * C);
    }

    // ---- 5) grouped Wo-all: xb = emb + ctx @ Wo^T ----
    {
        G4 g;
        int cum = 0;
        for (int i = 0; i < 4; i++) {
            const int C = Cs[i];
            const long C2 = (long)C * C;
            g.A[i] = cx2 + co[i]; g.B[i] = (const bf16*)(wp + wb[i] + 4 * C2);
            g.Cv[i] = xball + co[i];
            g.bias[i] = nullptr; g.res[i] = emb[i];
            g.M[i] = NT; g.N[i] = C; g.K[i] = C;
            g.lda[i] = C; g.ldb[i] = C; g.ldc[i] = C;
            g.nbx[i] = (C >= 128) ? C / 128 : 1;
            g.cum[i] = cum; cum += g.nbx[i] * 26;
        }
        g.cum[4] = cum;
        mfma4g<bf16, float><<<cum, 256, 0, stream>>>(g, 0);
    }
    // ---- 6) grouped LN ----
    {
        LR4 a;
        for (int i = 0; i < 4; i++) {
            a.X[i] = xball + co[i]; a.g[i] = fng[i]; a.b[i] = fnb[i];
            a.Y[i] = cx3 + co[i]; a.C[i] = Cs[i];
        }
        ln_rows4_kernel<<<dim3(3136, 4), 256, 0, stream>>>(a);
    }
    // ---- 7) grouped FFN1: hid = gelu(lnx @ w1^T + b1) ----
    {
        G4 g;
        int cum = 0;
        for (int i = 0; i < 4; i++) {
            const int C = Cs[i];
            const long C2 = (long)C * C;
            g.A[i] = cx3 + co[i]; g.B[i] = (const bf16*)(wp + wb[i] + 5 * C2);
            g.Cv[i] = hid + ho[i];
            g.bias[i] = b1[i]; g.res[i] = nullptr;
            g.M[i] = NT; g.N[i] = 4 * C; g.K[i] = C;
            g.lda[i] = C; g.ldb[i] = C; g.ldc[i] = 4 * C;
            g.nbx[i] = 4 * C / 128;
            g.cum[i] = cum; cum += g.nbx[i] * 26;
        }
        g.cum[4] = cum;
        mfma4g<bf16, float><<<cum, 256, 0, stream>>>(g, 1);
    }
    // ---- 8) grouped FFN2: out = xb + hid @ w2^T + b2 (fp32) ----
    {
        G4 g;
        int cum = 0;
        for (int i = 0; i < 4; i++) {
            const int C = Cs[i];
            const long C2 = (long)C * C;
            g.A[i] = hid + ho[i]; g.B[i] = (const bf16*)(wp + wb[i] + 9 * C2);
            g.Cv[i] = out + ooff[i];
            g.bias[i] = b2[i]; g.res[i] = xball + co[i];
            g.M[i] = NT; g.N[i] = C; g.K[i] = 4 * C;
            g.lda[i] = 4 * C; g.ldb[i] = 4 * C; g.ldc[i] = C;
            g.nbx[i] = (C >= 128) ? C / 128 : 1;
            g.cum[i] = cum; cum += g.nbx[i] * 26;
        }
        g.cum[4] = cum;
        mfma4g<float, bf16><<<cum, 256, 0, stream>>>(g, 0);
    }
}

// Round 9
// 721.504 us; speedup vs baseline: 1.2707x; 1.0263x over previous
//
#include <hip/hip_runtime.h>
#include <hip/hip_bf16.h>

// Block_ViT on MI355X — round 21: fused K+V projection as ONE 256^2 8-wave
// 4-phase mfma8kv GEMM (N=7680 = Wk||Wv stacked), R13-proven (r>>1)&3 swizzle,
// 2D XCD partition (qx=8,hy=7 on padded 32x14 grid, dead blocks early-exit),
// all-fast-path staging (pads readable by layout). Epilogue: n<3840 -> KT
// transposed store; else -> Vb2. Rationale: 128^2/4-wave is LDS-read-bound at
// ~27% MfmaUtil (31 B/KFLOP vs 112 B/cy supply); 256^2/8-wave needs 23 B/KFLOP
// at 1 block/CU -> compute-bound. 448 blocks >= 256 CUs (R15 had only 208).
// Everything else = R20 (grouped FFN phase, fused IN stats, mfma4 attention).
// B=4, N=784, H=4, Cs={64,128,256,512}, KV=960, NT=3136. fp32 in/out.

using bf16 = __hip_bfloat16;
typedef __attribute__((ext_vector_type(8))) short short8;   // 8 bf16 (4 VGPRs)
typedef __attribute__((ext_vector_type(4))) float f32x4;    // MFMA acc

__device__ inline float bf2f(unsigned short u) {
    return __uint_as_float(((unsigned int)u) << 16);
}
__device__ inline unsigned short f2b(float f) {            // RTNE fp32->bf16
    unsigned int u = __float_as_uint(f);
    return (unsigned short)((u + 0x7fffu + ((u >> 16) & 1u)) >> 16);
}
__device__ inline float ld1f(const float* p) { return *p; }
__device__ inline float ld1f(const bf16* p) { return bf2f(*(const unsigned short*)p); }
__device__ inline void st1(float* p, float v) { *p = v; }
__device__ inline void st1(bf16* p, float v) { *((unsigned short*)p) = f2b(v); }
__device__ inline float4 ld4f(const bf16* p) {
    ushort4 u = *(const ushort4*)p;
    return make_float4(bf2f(u.x), bf2f(u.y), bf2f(u.z), bf2f(u.w));
}

// async global->LDS, 16 B per lane; LDS dest = wave-uniform base + lane*16
__device__ __forceinline__ void cp16(const void* g, void* l) {
    __builtin_amdgcn_global_load_lds(
        (const __attribute__((address_space(1))) void*)g,
        (__attribute__((address_space(3))) void*)l, 16, 0, 0);
}

// ---- block reductions (256 threads = 4 waves) ----
__device__ inline float blockSum256(float v, float* red) {
    #pragma unroll
    for (int o = 32; o > 0; o >>= 1) v += __shfl_down(v, o);
    int t = threadIdx.x;
    if ((t & 63) == 0) red[t >> 6] = v;
    __syncthreads();
    float r = red[0] + red[1] + red[2] + red[3];
    __syncthreads();
    return r;
}
__device__ inline float blockMax256(float v, float* red) {
    #pragma unroll
    for (int o = 32; o > 0; o >>= 1) v = fmaxf(v, __shfl_down(v, o));
    int t = threadIdx.x;
    if ((t & 63) == 0) red[t >> 6] = v;
    __syncthreads();
    float r = fmaxf(fmaxf(red[0], red[1]), fmaxf(red[2], red[3]));
    __syncthreads();
    return r;
}

// ---- fp32 -> bf16 conversion of ALL weights (18 segments) + stat zeroing ----
struct CvtN {
    const float* s[18];
    unsigned short* d[18];
    long n[18];
    float* z;             // zero 128 floats (4 branches x 32 IN stats)
};
__global__ __launch_bounds__(256)
void cvtn_kernel(CvtN a) {
    if (a.z && blockIdx.x == 0 && threadIdx.x < 128) a.z[threadIdx.x] = 0.f;
    long tid = (long)blockIdx.x * 256 + threadIdx.x;
    long stride = (long)gridDim.x * 256;
    for (int g = 0; g < 18; g++) {
        const float* s = a.s[g];
        unsigned short* d = a.d[g];
        long n = a.n[g];
        for (long i = tid * 4; i < n; i += stride * 4) {
            float4 v = *(const float4*)(s + i);
            *(ushort4*)(d + i) = make_ushort4(f2b(v.x), f2b(v.y), f2b(v.z), f2b(v.w));
        }
    }
}

// ==== mfma8kv: fused K+V projection, 256x256 tile, 8 waves, BK=64 ====
// A = ea [3136x960] (rows readable to 3328+), B = wkv [7680x960] contiguous.
// M=3136, N=7680, K=960. Grid (32,14): dead blocks (m0>=M || n0>=N) exit.
// 2D XCD partition qx=8, hy=7. Swizzle h(r)=(r>>1)&3, both sides, 0-conflict.
// Pipeline (R15-verified): 4 phases/K-tile, each {frag ds_read || stage one
// half of next tile -> bar -> lgkm0 -> setprio 16 MFMA -> [vmcnt(4) at p1/p3]
// -> bar}. Queue trace: end-p3 vmcnt(4) drains next tile's k0 halves.
// Epilogue: gn < 3840 -> KT[gn][gm] transposed ushort4; else Vb2[gm][gn-3840].
__global__ __launch_bounds__(512, 2)
void mfma8kv(const bf16* __restrict__ A, const bf16* __restrict__ B,
             bf16* __restrict__ KT, bf16* __restrict__ V) {
    __shared__ short Asl[2][2][256][32];
    __shared__ short Bsl[2][2][256][32];
    const int M = 3136, N = 7680, lda = 960, ldb = 960;
    int orig = (int)blockIdx.y * 32 + (int)blockIdx.x;
    int c = orig & 7, r2 = orig >> 3;
    int bx = (c & 3) * 8 + (r2 & 7);
    int by = (c >> 2) * 7 + (r2 >> 3);
    int m0 = by * 256, n0 = bx * 256;
    if (m0 >= M || n0 >= N) return;
    int t = threadIdx.x, lane = t & 63, wv = t >> 6;   // wv 0..7
    int col = lane & 15, quad = lane >> 4;
    int wm = wv >> 2, wn = wv & 3;                     // 2(M) x 4(N)
    f32x4 acc[8][4];
    #pragma unroll
    for (int i = 0; i < 8; i++)
        #pragma unroll
        for (int j = 0; j < 4; j++) acc[i][j] = (f32x4){0.f, 0.f, 0.f, 0.f};

    int srow = lane >> 2;                              // row within 16-row grp
    int scol = ((lane & 3) ^ ((lane >> 3) & 3)) << 3;  // src col ^ h(row)
    int rslot = (quad ^ ((col >> 1) & 3)) << 3;        // read slot ^ h(row)

    auto stageA = [&](int s2, int kt, int kh) {
        int k0 = kt * 64 + kh * 32;
        #pragma unroll
        for (int r = 0; r < 2; r++) {
            int R0 = (r * 8 + wv) * 16;
            cp16(A + (long)(m0 + R0 + srow) * lda + k0 + scol, &Asl[s2][kh][R0][0]);
        }
    };
    auto stageB = [&](int s2, int kt, int kh) {
        int k0 = kt * 64 + kh * 32;
        #pragma unroll
        for (int r = 0; r < 2; r++) {
            int R0 = (r * 8 + wv) * 16;
            cp16(B + (long)(n0 + R0 + srow) * ldb + k0 + scol, &Bsl[s2][kh][R0][0]);
        }
    };

    const int nk = 15;               // K=960 / 64
    stageA(0, 0, 0); stageB(0, 0, 0); stageA(0, 0, 1); stageB(0, 0, 1);
    __syncthreads();

    for (int kt = 0; kt < nk; kt++) {
        int cur = kt & 1, nxt = cur ^ 1;
        bool st = (kt + 1 < nk);
        short8 af[8], bf8[4];
        // ---- phase 0: sk0, mi0-3; stage A-k0(next) ----
        #pragma unroll
        for (int ni = 0; ni < 4; ni++)
            bf8[ni] = *(const short8*)&Bsl[cur][0][wn * 64 + ni * 16 + col][rslot];
        #pragma unroll
        for (int mi = 0; mi < 4; mi++)
            af[mi] = *(const short8*)&Asl[cur][0][wm * 128 + mi * 16 + col][rslot];
        if (st) stageA(nxt, kt + 1, 0);
        __builtin_amdgcn_s_barrier();
        asm volatile("s_waitcnt lgkmcnt(0)" ::: "memory");
        __builtin_amdgcn_sched_barrier(0);
        __builtin_amdgcn_s_setprio(1);
        #pragma unroll
        for (int mi = 0; mi < 4; mi++)
            #pragma unroll
            for (int ni = 0; ni < 4; ni++)
                acc[mi][ni] = __builtin_amdgcn_mfma_f32_16x16x32_bf16(
                    af[mi], bf8[ni], acc[mi][ni], 0, 0, 0);
        __builtin_amdgcn_s_setprio(0);
        __builtin_amdgcn_s_barrier();
        // ---- phase 1: sk0, mi4-7; stage B-k0(next) ----
        #pragma unroll
        for (int mi = 4; mi < 8; mi++)
            af[mi] = *(const short8*)&Asl[cur][0][wm * 128 + mi * 16 + col][rslot];
        if (st) stageB(nxt, kt + 1, 0);
        __builtin_amdgcn_s_barrier();
        asm volatile("s_waitcnt lgkmcnt(0)" ::: "memory");
        __builtin_amdgcn_sched_barrier(0);
        __builtin_amdgcn_s_setprio(1);
        #pragma unroll
        for (int mi = 4; mi < 8; mi++)
            #pragma unroll
            for (int ni = 0; ni < 4; ni++)
                acc[mi][ni] = __builtin_amdgcn_mfma_f32_16x16x32_bf16(
                    af[mi], bf8[ni], acc[mi][ni], 0, 0, 0);
        __builtin_amdgcn_s_setprio(0);
        if (st) asm volatile("s_waitcnt vmcnt(4)" ::: "memory");
        else    asm volatile("s_waitcnt vmcnt(0)" ::: "memory");
        __builtin_amdgcn_s_barrier();
        // ---- phase 2: sk1, mi0-3; stage A-k1(next) ----
        #pragma unroll
        for (int ni = 0; ni < 4; ni++)
            bf8[ni] = *(const short8*)&Bsl[cur][1][wn * 64 + ni * 16 + col][rslot];
        #pragma unroll
        for (int mi = 0; mi < 4; mi++)
            af[mi] = *(const short8*)&Asl[cur][1][wm * 128 + mi * 16 + col][rslot];
        if (st) stageA(nxt, kt + 1, 1);
        __builtin_amdgcn_s_barrier();
        asm volatile("s_waitcnt lgkmcnt(0)" ::: "memory");
        __builtin_amdgcn_sched_barrier(0);
        __builtin_amdgcn_s_setprio(1);
        #pragma unroll
        for (int mi = 0; mi < 4; mi++)
            #pragma unroll
            for (int ni = 0; ni < 4; ni++)
                acc[mi][ni] = __builtin_amdgcn_mfma_f32_16x16x32_bf16(
                    af[mi], bf8[ni], acc[mi][ni], 0, 0, 0);
        __builtin_amdgcn_s_setprio(0);
        __builtin_amdgcn_s_barrier();
        // ---- phase 3: sk1, mi4-7; stage B-k1(next) ----
        #pragma unroll
        for (int mi = 4; mi < 8; mi++)
            af[mi] = *(const short8*)&Asl[cur][1][wm * 128 + mi * 16 + col][rslot];
        if (st) stageB(nxt, kt + 1, 1);
        __builtin_amdgcn_s_barrier();
        asm volatile("s_waitcnt lgkmcnt(0)" ::: "memory");
        __builtin_amdgcn_sched_barrier(0);
        __builtin_amdgcn_s_setprio(1);
        #pragma unroll
        for (int mi = 4; mi < 8; mi++)
            #pragma unroll
            for (int ni = 0; ni < 4; ni++)
                acc[mi][ni] = __builtin_amdgcn_mfma_f32_16x16x32_bf16(
                    af[mi], bf8[ni], acc[mi][ni], 0, 0, 0);
        __builtin_amdgcn_s_setprio(0);
        if (st) asm volatile("s_waitcnt vmcnt(4)" ::: "memory");
        __builtin_amdgcn_s_barrier();
    }
    // epilogue — C/D layout: col=lane&15, row=quad*4+reg [m89/m91]
    #pragma unroll
    for (int mi = 0; mi < 8; mi++) {
        int gmB = m0 + wm * 128 + mi * 16 + quad * 4;
        #pragma unroll
        for (int ni = 0; ni < 4; ni++) {
            int gn = n0 + wn * 64 + ni * 16 + col;
            if (gn < 3840) {                 // K half -> KT[gn][gm] (transposed)
                if (gmB < M) {
                    ushort4 w = make_ushort4(f2b(acc[mi][ni][0]), f2b(acc[mi][ni][1]),
                                             f2b(acc[mi][ni][2]), f2b(acc[mi][ni][3]));
                    *(ushort4*)((unsigned short*)KT + (long)gn * M + gmB) = w;
                }
            } else {                          // V half -> Vb2[gm][gn-3840]
                int vn = gn - 3840;
                #pragma unroll
                for (int r = 0; r < 4; r++) {
                    int gm = gmB + r;
                    if (gm < M) st1(V + (long)gm * 3840 + vn, acc[mi][ni][r]);
                }
            }
        }
    }
}

// ==== mfma4: 128x128, 4 waves (2x2), BK=32, 3 LDS slots (R19, unchanged) ====
template <class CT, class RT, bool TO>
__global__ __launch_bounds__(256, 3)
void mfma4(const bf16* __restrict__ A, long Ah, long Ab, int lda,
           const bf16* __restrict__ B, long Bh, long Bb, int ldb,
           CT* __restrict__ Cp, long Ch, long Cb, int ldc,
           const float* __restrict__ bias, const RT* __restrict__ res,
           int M, int N, int K, int Mpad, int Npad, int qx, int hy,
           float alpha, int dogelu, float* __restrict__ stat) {
    __shared__ short Asl[3][128][32];
    __shared__ short Bsl[3][128][32];
    int gx = gridDim.x, gy = gridDim.y;
    int orig = ((int)blockIdx.z * gy + (int)blockIdx.y) * gx + (int)blockIdx.x;
    int bx, by, bz;
    if (qx) {
        int c = orig & 7, r2 = orig >> 3;
        bx = (c & 3) * qx + r2 % qx;
        by = (c >> 2) * hy + r2 / qx;
        bz = 0;
    } else {
        int nxy = gx * gy, nwg = nxy * (int)gridDim.z;
        int q = nwg >> 3, r8 = nwg & 7;
        int xcd = orig & 7, pos = orig >> 3;
        int wgid = (xcd < r8 ? xcd * (q + 1) : r8 * (q + 1) + (xcd - r8) * q) + pos;
        bz = wgid / nxy;
        int rem = wgid - bz * nxy;
        by = rem / gx; bx = rem - by * gx;
    }
    int z = bz;
    A += (long)(z & 3) * Ah + (long)(z >> 2) * Ab;
    B += (long)(z & 3) * Bh + (long)(z >> 2) * Bb;
    Cp += (long)(z & 3) * Ch + (long)(z >> 2) * Cb;
    int m0 = by * 128, n0 = bx * 128;
    int t = threadIdx.x, lane = t & 63, wv = t >> 6;
    int col = lane & 15, quad = lane >> 4;
    int wm = wv >> 1, wn = wv & 1;
    f32x4 acc[4][4];
    #pragma unroll
    for (int i = 0; i < 4; i++)
        #pragma unroll
        for (int j = 0; j < 4; j++) acc[i][j] = (f32x4){0.f, 0.f, 0.f, 0.f};

    const bool fA = (m0 + 128 <= Mpad);
    const bool fB = (n0 + 128 <= Npad);
    int srow = lane >> 2;
    int scol = ((lane & 3) ^ ((lane >> 3) & 3)) << 3;
    int rslot = (quad ^ ((col >> 1) & 3)) << 3;

    auto stageA = [&](int s3, int kt) {
        int k0 = kt * 32;
        if (fA && k0 + 32 <= K) {
            #pragma unroll
            for (int r = 0; r < 2; r++) {
                int R0 = (r * 4 + wv) * 16;
                cp16(A + (long)(m0 + R0 + srow) * lda + k0 + scol, &Asl[s3][R0][0]);
            }
        } else {
            #pragma unroll
            for (int r = 0; r < 2; r++) {
                int idx = r * 256 + t;
                int row = idx >> 2, sl = idx & 3;
                int f2 = (row >> 1) & 3;
                short8 v = {};
                if (m0 + row < M && k0 + sl * 8 < K)
                    v = *(const short8*)(A + (long)(m0 + row) * lda + k0 + sl * 8);
                *(short8*)&Asl[s3][row][(sl ^ f2) * 8] = v;
            }
            asm volatile("s_waitcnt lgkmcnt(0)" ::: "memory");
        }
    };
    auto stageB = [&](int s3, int kt) {
        int k0 = kt * 32;
        if (fB && k0 + 32 <= K) {
            #pragma unroll
            for (int r = 0; r < 2; r++) {
                int R0 = (r * 4 + wv) * 16;
                cp16(B + (long)(n0 + R0 + srow) * ldb + k0 + scol, &Bsl[s3][R0][0]);
            }
        } else {
            #pragma unroll
            for (int r = 0; r < 2; r++) {
                int idx = r * 256 + t;
                int row = idx >> 2, sl = idx & 3;
                int f2 = (row >> 1) & 3;
                short8 v = {};
                if (n0 + row < N && k0 + sl * 8 < K)
                    v = *(const short8*)(B + (long)(n0 + row) * ldb + k0 + sl * 8);
                *(short8*)&Bsl[s3][row][(sl ^ f2) * 8] = v;
            }
            asm volatile("s_waitcnt lgkmcnt(0)" ::: "memory");
        }
    };

    int nk = (K + 31) >> 5;
    stageA(0, 0); stageB(0, 0);
    stageA(1, 1); stageB(1, 1);
    __syncthreads();

    for (int kt = 0; kt < nk; kt++) {
        int cur = kt % 3;
        short8 af[4], bf4[4];
        #pragma unroll
        for (int mi = 0; mi < 4; mi++)
            af[mi] = *(const short8*)&Asl[cur][wm * 64 + mi * 16 + col][rslot];
        #pragma unroll
        for (int ni = 0; ni < 4; ni++)
            bf4[ni] = *(const short8*)&Bsl[cur][wn * 64 + ni * 16 + col][rslot];
        int pend = 0;
        if (kt + 2 < nk) {
            int s3 = (kt + 2) % 3;
            stageA(s3, kt + 2); stageB(s3, kt + 2);
            if ((kt + 2) * 32 + 32 <= K) pend = (fA ? 2 : 0) + (fB ? 2 : 0);
        }
        __builtin_amdgcn_s_barrier();
        asm volatile("s_waitcnt lgkmcnt(0)" ::: "memory");
        __builtin_amdgcn_sched_barrier(0);
        __builtin_amdgcn_s_setprio(1);
        #pragma unroll
        for (int mi = 0; mi < 4; mi++)
            #pragma unroll
            for (int ni = 0; ni < 4; ni++)
                acc[mi][ni] = __builtin_amdgcn_mfma_f32_16x16x32_bf16(
                    af[mi], bf4[ni], acc[mi][ni], 0, 0, 0);
        __builtin_amdgcn_s_setprio(0);
        if (kt + 1 < nk) {
            if (pend == 4)      asm volatile("s_waitcnt vmcnt(4)" ::: "memory");
            else if (pend == 2) asm volatile("s_waitcnt vmcnt(2)" ::: "memory");
            else                asm volatile("s_waitcnt vmcnt(0)" ::: "memory");
            __builtin_amdgcn_s_barrier();
        }
    }
    float psum = 0.f, psq = 0.f;
    #pragma unroll
    for (int mi = 0; mi < 4; mi++) {
        int gmB = m0 + wm * 64 + mi * 16 + quad * 4;
        #pragma unroll
        for (int ni = 0; ni < 4; ni++) {
            int gn = n0 + wn * 64 + ni * 16 + col;
            if constexpr (TO) {
                if (gmB < M && gn < N) {
                    ushort4 w = make_ushort4(f2b(acc[mi][ni][0] * alpha),
                                             f2b(acc[mi][ni][1] * alpha),
                                             f2b(acc[mi][ni][2] * alpha),
                                             f2b(acc[mi][ni][3] * alpha));
                    *(ushort4*)((unsigned short*)Cp + (long)gn * ldc + gmB) = w;
                }
            } else {
                if (gn < N) {
                    float bz2 = bias ? bias[gn] : 0.f;
                    #pragma unroll
                    for (int r = 0; r < 4; r++) {
                        int gm = gmB + r;
                        if (gm < M) {
                            float v = acc[mi][ni][r] * alpha + bz2;
                            if (dogelu) v = 0.5f * v * (1.f + erff(v * 0.70710678118f));
                            if (res) v += ld1f(res + (long)gm * ldc + gn);
                            st1(Cp + (long)gm * ldc + gn, v);
                            psum += v; psq += v * v;
                        }
                    }
                }
            }
        }
    }
    if (stat) {
        __syncthreads();
        #pragma unroll
        for (int o = 32; o > 0; o >>= 1) {
            psum += __shfl_down(psum, o);
            psq  += __shfl_down(psq, o);
        }
        float* red = (float*)Asl;
        if ((t & 63) == 0) { red[wv] = psum; red[4 + wv] = psq; }
        __syncthreads();
        if (t == 0) {
            atomicAdd(&stat[2 * z],     red[0] + red[1] + red[2] + red[3]);
            atomicAdd(&stat[2 * z + 1], red[4] + red[5] + red[6] + red[7]);
        }
    }
}

// ==== mfma4g: grouped (4-problem) 128x128 GEMM, pure fast path (R20) ====
struct G4 {
    const bf16* A[4]; const bf16* B[4]; void* Cv[4];
    const float* bias[4]; const void* res[4];
    int M[4], N[4], K[4], lda[4], ldb[4], ldc[4], nbx[4];
    int cum[5];
};
template <class CT, class RT>
__global__ __launch_bounds__(256, 3)
void mfma4g(G4 gp, int dogelu) {
    __shared__ short Asl[3][128][32];
    __shared__ short Bsl[3][128][32];
    int nwg = gridDim.x;
    int orig = blockIdx.x;
    int q = nwg >> 3, r8 = nwg & 7;
    int xcd = orig & 7, pos = orig >> 3;
    int wgid = (xcd < r8 ? xcd * (q + 1) : r8 * (q + 1) + (xcd - r8) * q) + pos;
    int gi = 0;
    if (wgid >= gp.cum[1]) gi = 1;
    if (wgid >= gp.cum[2]) gi = 2;
    if (wgid >= gp.cum[3]) gi = 3;
    int local = wgid - gp.cum[gi];
    int nbx = gp.nbx[gi];
    int by = local / nbx, bx = local - by * nbx;
    const bf16* A = gp.A[gi];
    const bf16* B = gp.B[gi];
    CT* Cp = (CT*)gp.Cv[gi];
    const float* bias = gp.bias[gi];
    const RT* res = (const RT*)gp.res[gi];
    int M = gp.M[gi], N = gp.N[gi], K = gp.K[gi];
    int lda = gp.lda[gi], ldb = gp.ldb[gi], ldc = gp.ldc[gi];
    int m0 = by * 128, n0 = bx * 128;
    int t = threadIdx.x, lane = t & 63, wv = t >> 6;
    int col = lane & 15, quad = lane >> 4;
    int wm = wv >> 1, wn = wv & 1;
    f32x4 acc[4][4];
    #pragma unroll
    for (int i = 0; i < 4; i++)
        #pragma unroll
        for (int j = 0; j < 4; j++) acc[i][j] = (f32x4){0.f, 0.f, 0.f, 0.f};

    int srow = lane >> 2;
    int scol = ((lane & 3) ^ ((lane >> 3) & 3)) << 3;
    int rslot = (quad ^ ((col >> 1) & 3)) << 3;

    auto stageA = [&](int s3, int kt) {
        int k0 = kt * 32;
        #pragma unroll
        for (int r = 0; r < 2; r++) {
            int R0 = (r * 4 + wv) * 16;
            cp16(A + (long)(m0 + R0 + srow) * lda + k0 + scol, &Asl[s3][R0][0]);
        }
    };
    auto stageB = [&](int s3, int kt) {
        int k0 = kt * 32;
        #pragma unroll
        for (int r = 0; r < 2; r++) {
            int R0 = (r * 4 + wv) * 16;
            cp16(B + (long)(n0 + R0 + srow) * ldb + k0 + scol, &Bsl[s3][R0][0]);
        }
    };

    int nk = K >> 5;
    stageA(0, 0); stageB(0, 0);
    stageA(1, 1); stageB(1, 1);
    __syncthreads();

    for (int kt = 0; kt < nk; kt++) {
        int cur = kt % 3;
        short8 af[4], bf4[4];
        #pragma unroll
        for (int mi = 0; mi < 4; mi++)
            af[mi] = *(const short8*)&Asl[cur][wm * 64 + mi * 16 + col][rslot];
        #pragma unroll
        for (int ni = 0; ni < 4; ni++)
            bf4[ni] = *(const short8*)&Bsl[cur][wn * 64 + ni * 16 + col][rslot];
        bool st = (kt + 2 < nk);
        if (st) {
            int s3 = (kt + 2) % 3;
            stageA(s3, kt + 2); stageB(s3, kt + 2);
        }
        __builtin_amdgcn_s_barrier();
        asm volatile("s_waitcnt lgkmcnt(0)" ::: "memory");
        __builtin_amdgcn_sched_barrier(0);
        __builtin_amdgcn_s_setprio(1);
        #pragma unroll
        for (int mi = 0; mi < 4; mi++)
            #pragma unroll
            for (int ni = 0; ni < 4; ni++)
                acc[mi][ni] = __builtin_amdgcn_mfma_f32_16x16x32_bf16(
                    af[mi], bf4[ni], acc[mi][ni], 0, 0, 0);
        __builtin_amdgcn_s_setprio(0);
        if (kt + 1 < nk) {
            if (st) asm volatile("s_waitcnt vmcnt(4)" ::: "memory");
            else    asm volatile("s_waitcnt vmcnt(0)" ::: "memory");
            __builtin_amdgcn_s_barrier();
        }
    }
    #pragma unroll
    for (int mi = 0; mi < 4; mi++) {
        int gmB = m0 + wm * 64 + mi * 16 + quad * 4;
        #pragma unroll
        for (int ni = 0; ni < 4; ni++) {
            int gn = n0 + wn * 64 + ni * 16 + col;
            if (gn < N) {
                float bz2 = bias ? bias[gn] : 0.f;
                #pragma unroll
                for (int r = 0; r < 4; r++) {
                    int gm = gmB + r;
                    if (gm < M) {
                        float v = acc[mi][ni][r] + bz2;
                        if (dogelu) v = 0.5f * v * (1.f + erff(v * 0.70710678118f));
                        if (res) v += ld1f(res + (long)gm * ldc + gn);
                        st1(Cp + (long)gm * ldc + gn, v);
                    }
                }
            }
        }
    }
}

// ==== mfma2 (R13 form) + optional fused stats — C=64 attention only ====
template <int TM, int TN, class CT, class RT, bool TO>
__global__ __launch_bounds__(256)
void mfma2(const bf16* __restrict__ A, long Ah, long Ab, int lda,
           const bf16* __restrict__ B, long Bh, long Bb, int ldb,
           CT* __restrict__ Cp, long Ch, long Cb, int ldc,
           const float* __restrict__ bias, const RT* __restrict__ res,
           int M, int N, int K, float alpha, int dogelu,
           float* __restrict__ stat) {
    constexpr int MI = TM / 32, NI = TN / 32;
    __shared__ short As[2][TM * 32];
    __shared__ short Bs[2][TN * 32];
    int z = blockIdx.z;
    A += (long)(z & 3) * Ah + (long)(z >> 2) * Ab;
    B += (long)(z & 3) * Bh + (long)(z >> 2) * Bb;
    Cp += (long)(z & 3) * Ch + (long)(z >> 2) * Cb;
    int m0 = blockIdx.y * TM, n0 = blockIdx.x * TN;
    int t = threadIdx.x, lane = t & 63, wv = t >> 6;
    int col = lane & 15, quad = lane >> 4;
    int wm = wv >> 1, wn = wv & 1;
    f32x4 acc[MI][NI];
    #pragma unroll
    for (int i = 0; i < MI; i++)
        #pragma unroll
        for (int j = 0; j < NI; j++) acc[i][j] = (f32x4){0.f, 0.f, 0.f, 0.f};

    const bool fastblk = (m0 + TM <= M) && (n0 + TN <= N);
    int lrow = lane >> 2;
    int lcol = ((lane & 3) ^ ((lane >> 3) & 3)) << 3;
    int sr = t >> 2;
    int swz = ((t & 3) ^ ((t >> 3) & 3)) << 3;
    int sdst = (t & 3) << 3;
    int rdslot = (quad ^ ((col >> 1) & 3)) << 3;

    auto stage = [&](int b, int k0) {
        if (fastblk && (k0 + 32 <= K)) {
            #pragma unroll
            for (int u = 0; u < TM / 64; u++) {
                int c = wv + 4 * u;
                int r = c * 16 + lrow;
                cp16(A + (long)(m0 + r) * lda + k0 + lcol, &As[b][c * 512]);
            }
            #pragma unroll
            for (int u = 0; u < TN / 64; u++) {
                int c = wv + 4 * u;
                int r = c * 16 + lrow;
                cp16(B + (long)(n0 + r) * ldb + k0 + lcol, &Bs[b][c * 512]);
            }
        } else {
            #pragma unroll
            for (int u = 0; u < TM / 64; u++) {
                int r = sr + u * 64;
                float4 v = make_float4(0.f, 0.f, 0.f, 0.f);
                if (m0 + r < M && k0 + swz < K)
                    v = *(const float4*)(A + (long)(m0 + r) * lda + k0 + swz);
                *(float4*)&As[b][r * 32 + sdst] = v;
            }
            #pragma unroll
            for (int u = 0; u < TN / 64; u++) {
                int r = sr + u * 64;
                float4 v = make_float4(0.f, 0.f, 0.f, 0.f);
                if (n0 + r < N && k0 + swz < K)
                    v = *(const float4*)(B + (long)(n0 + r) * ldb + k0 + swz);
                *(float4*)&Bs[b][r * 32 + sdst] = v;
            }
        }
    };

    int nk = (K + 31) >> 5;
    stage(0, 0);
    __syncthreads();
    int cur = 0;
    for (int s = 0; s < nk; s++) {
        if (s + 1 < nk) stage(cur ^ 1, (s + 1) * 32);
        short8 af[MI], bfr[NI];
        #pragma unroll
        for (int mi = 0; mi < MI; mi++)
            af[mi] = *(const short8*)&As[cur][(wm * (TM / 2) + mi * 16 + col) * 32 + rdslot];
        #pragma unroll
        for (int ni = 0; ni < NI; ni++)
            bfr[ni] = *(const short8*)&Bs[cur][(wn * (TN / 2) + ni * 16 + col) * 32 + rdslot];
        #pragma unroll
        for (int mi = 0; mi < MI; mi++)
            #pragma unroll
            for (int ni = 0; ni < NI; ni++)
                acc[mi][ni] = __builtin_amdgcn_mfma_f32_16x16x32_bf16(
                    af[mi], bfr[ni], acc[mi][ni], 0, 0, 0);
        if (s + 1 < nk) __syncthreads();
        cur ^= 1;
    }
    float psum = 0.f, psq = 0.f;
    #pragma unroll
    for (int mi = 0; mi < MI; mi++) {
        int gmB = m0 + wm * (TM / 2) + mi * 16 + quad * 4;
        #pragma unroll
        for (int ni = 0; ni < NI; ni++) {
            int gn = n0 + wn * (TN / 2) + ni * 16 + col;
            if constexpr (TO) {
                if (gmB < M && gn < N) {
                    ushort4 w = make_ushort4(f2b(acc[mi][ni][0] * alpha),
                                             f2b(acc[mi][ni][1] * alpha),
                                             f2b(acc[mi][ni][2] * alpha),
                                             f2b(acc[mi][ni][3] * alpha));
                    *(ushort4*)((unsigned short*)Cp + (long)gn * ldc + gmB) = w;
                }
            } else {
                if (gn < N) {
                    float bz = bias ? bias[gn] : 0.f;
                    #pragma unroll
                    for (int r = 0; r < 4; r++) {
                        int gm = gmB + r;
                        if (gm < M) {
                            float v = acc[mi][ni][r] * alpha + bz;
                            if (dogelu) v = 0.5f * v * (1.f + erff(v * 0.70710678118f));
                            if (res) v += ld1f(res + (long)gm * ldc + gn);
                            st1(Cp + (long)gm * ldc + gn, v);
                            psum += v; psq += v * v;
                        }
                    }
                }
            }
        }
    }
    if (stat) {
        __syncthreads();
        #pragma unroll
        for (int o = 32; o > 0; o >>= 1) {
            psum += __shfl_down(psum, o);
            psq  += __shfl_down(psq, o);
        }
        float* red = (float*)As;
        if ((t & 63) == 0) { red[wv] = psum; red[4 + wv] = psq; }
        __syncthreads();
        if (t == 0) {
            atomicAdd(&stat[2 * z],     red[0] + red[1] + red[2] + red[3]);
            atomicAdd(&stat[2 * z + 1], red[4] + red[5] + red[6] + red[7]);
        }
    }
}

// ---- merged LayerNorms: concat-LN (ea) + 4 branch first-LNs ----
struct LNA {
    const float* e[4];
    const float* ag[4];
    const float* ab[4];
    const float* cg;
    const float* cbb;
    bf16* y[4];
    bf16* ea;
};
__global__ __launch_bounds__(256)
void ln_all_kernel(LNA a) {
    __shared__ float x[960];
    __shared__ float red[4];
    long row = blockIdx.x;
    int t = threadIdx.x;
    const int off[5] = {0, 64, 192, 448, 960};
    {
        const float* p1 = a.e[0] + row * 64;
        const float* p2 = a.e[1] + row * 128;
        const float* p3 = a.e[2] + row * 256;
        const float* p4 = a.e[3] + row * 512;
        if (t < 64) x[t] = p1[t];
        for (int i = t; i < 128; i += 256) x[64 + i]  = p2[i];
        for (int i = t; i < 256; i += 256) x[192 + i] = p3[i];
        for (int i = t; i < 512; i += 256) x[448 + i] = p4[i];
    }
    __syncthreads();
    float ssum[4], ssq[4];
    #pragma unroll
    for (int br = 0; br < 4; br++) {
        float s = 0.f, q = 0.f;
        for (int i = off[br] + t; i < off[br + 1]; i += 256) {
            float v = x[i]; s += v; q += v * v;
        }
        ssum[br] = blockSum256(s, red);
        ssq[br]  = blockSum256(q, red);
    }
    float S1 = ssum[0] + ssum[1] + ssum[2] + ssum[3];
    float S2 = ssq[0] + ssq[1] + ssq[2] + ssq[3];
    float muA = S1 * (1.f / 960.f);
    float rA = rsqrtf(S2 * (1.f / 960.f) - muA * muA + 1e-6f);
    for (int i = t; i < 960; i += 256)
        st1(a.ea + row * 960 + i, (x[i] - muA) * rA * a.cg[i] + a.cbb[i]);
    #pragma unroll
    for (int br = 0; br < 4; br++) {
        int C = off[br + 1] - off[br];
        float mu = ssum[br] / C;
        float rr = rsqrtf(ssq[br] / C - mu * mu + 1e-6f);
        const float* g = a.ag[br];
        const float* b = a.ab[br];
        bf16* y = a.y[br] + row * C;
        for (int i = t; i < C; i += 256)
            st1(y + i, (x[off[br] + i] - mu) * rr * g[i] + b[i]);
    }
}

// ---- grouped row LayerNorm: grid (3136, 4) ----
struct LR4 {
    const bf16* X[4];
    const float* g[4];
    const float* b[4];
    bf16* Y[4];
    int C[4];
};
__global__ __launch_bounds__(256)
void ln_rows4_kernel(LR4 a) {
    __shared__ float x[512];
    __shared__ float red[4];
    int br = blockIdx.y;
    long row = blockIdx.x;
    int C = a.C[br];
    int t = threadIdx.x;
    const bf16* xr = a.X[br] + row * C;
    float s = 0.f, q = 0.f;
    for (int i = t; i < C; i += 256) { float v = ld1f(xr + i); x[i] = v; s += v; q += v * v; }
    float S1 = blockSum256(s, red), S2 = blockSum256(q, red);
    float mu = S1 / C;
    float r = rsqrtf(S2 / C - mu * mu + 1e-6f);
    const float* g = a.g[br];
    const float* b = a.b[br];
    bf16* y = a.Y[br] + row * C;
    for (int i = t; i < C; i += 256)
        st1(y + i, (x[i] - mu) * r * g[i] + b[i]);
}

// ---- ctx head-sum: ctx[i] = 0.25*sum_h tmp[h][i] ----
__global__ __launch_bounds__(256)
void ctx_sum_kernel(const bf16* __restrict__ tmp, bf16* __restrict__ ctx, long NTC) {
    long i = ((long)blockIdx.x * 256 + threadIdx.x) * 4;
    float4 a = ld4f(tmp + i);
    float4 b = ld4f(tmp + NTC + i);
    float4 c = ld4f(tmp + 2 * NTC + i);
    float4 d = ld4f(tmp + 3 * NTC + i);
    ushort4 o = make_ushort4(f2b((a.x + b.x + c.x + d.x) * 0.25f),
                             f2b((a.y + b.y + c.y + d.y) * 0.25f),
                             f2b((a.z + b.z + c.z + d.z) * 0.25f),
                             f2b((a.w + b.w + c.w + d.w) * 0.25f));
    *(ushort4*)(ctx + i) = o;
}

// ---- softmax over last dim (960) of S[b][C][3840]; rstd from fused stats ----
__global__ __launch_bounds__(256)
void softmax_kernel(bf16* __restrict__ S, const float* __restrict__ stat, int C) {
    __shared__ float x[960];
    __shared__ float red[4];
    long r = blockIdx.x;
    int t = threadIdx.x;
    int z = (int)(r / C);           // stats z: z&3=h, z>>2=b (matches S-GEMM)
    int d = (int)(r % C);
    float n = 960.f * (float)C;
    float s0 = stat[2 * z], q0 = stat[2 * z + 1];
    float mu = s0 / n;
    float rs = rsqrtf(q0 / n - mu * mu + 1e-5f);
    int h = z & 3, b = z >> 2;
    bf16* row = S + (long)b * C * 3840 + (long)d * 3840 + h * 960;
    float mx = -3.4e38f;
    for (int i = t; i < 960; i += 256) {
        float v = ld1f(row + i) * rs; x[i] = v; mx = fmaxf(mx, v);
    }
    float M = blockMax256(mx, red);
    float s = 0.f;
    for (int i = t; i < 960; i += 256) { float e = __expf(x[i] - M); x[i] = e; s += e; }
    float Ssum = blockSum256(s, red);
    float inv = 1.f / Ssum;
    for (int i = t; i < 960; i += 256) st1(row + i, x[i] * inv);
}

extern "C" void kernel_launch(void* const* d_in, const int* in_sizes, int n_in,
                              void* d_out, int out_size, void* d_ws, size_t ws_size,
                              hipStream_t stream) {
    (void)in_sizes; (void)n_in; (void)out_size; (void)ws_size;
    const int Cs[4] = {64, 128, 256, 512};
    const float *emb[4], *ang[4], *anb[4], *Wq[4], *Wo[4], *fng[4], *fnb[4], *w1[4], *b1[4], *w2[4], *b2[4];
    for (int i = 0; i < 4; i++) {
        const int base = i * 11;
        emb[i] = (const float*)d_in[base + 0];
        ang[i] = (const float*)d_in[base + 1];
        anb[i] = (const float*)d_in[base + 2];
        Wq[i]  = (const float*)d_in[base + 3];
        Wo[i]  = (const float*)d_in[base + 4];
        fng[i] = (const float*)d_in[base + 5];
        fnb[i] = (const float*)d_in[base + 6];
        w1[i]  = (const float*)d_in[base + 7];
        b1[i]  = (const float*)d_in[base + 8];
        w2[i]  = (const float*)d_in[base + 9];
        b2[i]  = (const float*)d_in[base + 10];
    }
    const float* anAg = (const float*)d_in[44];
    const float* anAb = (const float*)d_in[45];
    const float* Wk   = (const float*)d_in[46];
    const float* Wv   = (const float*)d_in[47];

    const int NT = 3136;
    char* wsb = (char*)d_ws;
    // ---- layout (bytes); liveness overlaps:
    //   wkv (57.2M..71.97M) + ea (71.97M..78.36M) dead after KV-GEMM;
    //   QT pool (57.2M) / Sb pool (70.07M) first written in branch loop;
    //   hid over KT; xball/cx3 over Vb2.
    unsigned short* wp = (unsigned short*)(wsb);          // 9,052,160
    float* statb = (float*)(wsb + 9052160);               // 128 floats
    bf16*  KT    = (bf16*)(wsb + 9053184);                // [3840][3136] 24.08MB
    bf16*  hid   = (bf16*)(wsb + 9053184);                // phase B (over KT)
    bf16*  Vb2   = (bf16*)(wsb + 33137664);               // [3136][3840] 24.08MB
    bf16*  xball = (bf16*)(wsb + 33137664);               // phase B (over Vb2)
    bf16*  cx3   = (bf16*)(wsb + 39158784);               // phase B (over Vb2)
    bf16*  QT    = (bf16*)(wsb + 57222144);               // QT/tmp pool 12.85MB
    bf16*  wkv   = (bf16*)(wsb + 57222144);               // [7680][960] 14.75MB early
    bf16*  Sb    = (bf16*)(wsb + 70067200);               // S pool 15.73MB
    bf16*  ea    = (bf16*)(wsb + 71967744);               // [3136][960] early
    bf16*  cxall = (bf16*)(wsb + 85795840);               // first-LN out 6.02MB
    bf16*  cx2   = (bf16*)(wsb + 91816960);               // ctx all branches 6.02MB

    const long wb[4] = {0, 53248, 266240, 1118208};       // 13*C^2 prefix (elems)
    const long co[4] = {0, 64L * NT, 192L * NT, 448L * NT}; // [NT][C] packed offs
    const long ho[4] = {0, 802816, 2408448, 5619712};     // hid offsets (elems)

    float* out = (float*)d_out;
    const long ooff[4] = {0, 200704, 602112, 1404928};
    const float scale = 0.03227486121f;  // 1/sqrt(960)

    // ---- 1) all weights -> bf16 + zero stats (wkv = Wk||Wv contiguous) ----
    {
        CvtN a;
        a.s[0] = Wk; a.d[0] = (unsigned short*)wkv;           a.n[0] = 3686400;
        a.s[1] = Wv; a.d[1] = (unsigned short*)wkv + 3686400; a.n[1] = 3686400;
        for (int i = 0; i < 4; i++) {
            const long C2 = (long)Cs[i] * Cs[i];
            a.s[2 + 4 * i] = Wq[i]; a.d[2 + 4 * i] = wp + wb[i];          a.n[2 + 4 * i] = 4 * C2;
            a.s[3 + 4 * i] = Wo[i]; a.d[3 + 4 * i] = wp + wb[i] + 4 * C2; a.n[3 + 4 * i] = C2;
            a.s[4 + 4 * i] = w1[i]; a.d[4 + 4 * i] = wp + wb[i] + 5 * C2; a.n[4 + 4 * i] = 4 * C2;
            a.s[5 + 4 * i] = w2[i]; a.d[5 + 4 * i] = wp + wb[i] + 9 * C2; a.n[5 + 4 * i] = 4 * C2;
        }
        a.z = statb;
        cvtn_kernel<<<1024, 256, 0, stream>>>(a);
    }
    // ---- 2) merged LayerNorms ----
    {
        LNA a;
        for (int i = 0; i < 4; i++) {
            a.e[i] = emb[i]; a.ag[i] = ang[i]; a.ab[i] = anb[i];
            a.y[i] = cxall + co[i];
        }
        a.cg = anAg; a.cbb = anAb; a.ea = ea;
        ln_all_kernel<<<3136, 256, 0, stream>>>(a);
    }
    // ---- 3) fused K+V projection (256^2 8-wave, one dispatch) ----
    mfma8kv<<<dim3(32, 14, 1), 512, 0, stream>>>(ea, wkv, KT, Vb2);

    // ---- 4) per-branch attention ----
    for (int i = 0; i < 4; i++) {
        const int C = Cs[i];
        const long C2 = (long)C * C;
        bf16* wqb = (bf16*)(wp + wb[i]);
        float* st = statb + 32 * i;
        if (C >= 128) {
            mfma4<bf16, float, true><<<dim3(C / 128, 26, 4), 256, 0, stream>>>(
                cxall + co[i], 0, 0, C, wqb, C2, 0, C, QT, (long)C * NT, 0, NT,
                nullptr, (const float*)nullptr, NT, C, C, 3328, C, 0, 0,
                1.f, 0, nullptr);
            mfma4<bf16, float, false><<<dim3(8, C / 128, 16), 256, 0, stream>>>(
                QT, (long)C * NT, 784, NT, KT, 3010560, 784, NT,
                Sb, 960, (long)C * 3840, 3840,
                nullptr, (const float*)nullptr, C, 960, 784, C, 1024, 0, 0,
                scale, 0, st);
        } else {
            mfma2<64, 64, bf16, float, true><<<dim3(1, 49, 4), 256, 0, stream>>>(
                cxall + co[i], 0, 0, C, wqb, C2, 0, C, QT, (long)C * NT, 0, NT,
                nullptr, (const float*)nullptr, NT, C, C, 1.f, 0, nullptr);
            mfma2<64, 64, bf16, float, false><<<dim3(15, 1, 16), 256, 0, stream>>>(
                QT, (long)C * NT, 784, NT, KT, 3010560, 784, NT,
                Sb, 960, (long)C * 3840, 3840,
                nullptr, (const float*)nullptr, C, 960, 784, scale, 0, st);
        }
        softmax_kernel<<<16 * C, 256, 0, stream>>>(Sb, st, C);
        if (C >= 128)
            mfma4<bf16, float, false><<<dim3(C / 128, 7, 16), 256, 0, stream>>>(
                Vb2, 960, 784L * 3840, 3840, Sb, 960, (long)C * 3840, 3840,
                QT, (long)NT * C, 784L * C, C,
                nullptr, (const float*)nullptr, 784, C, 960, 896, C, 0, 0,
                1.f, 0, nullptr);
        else
            mfma2<64, 64, bf16, float, false><<<dim3(1, 13, 16), 256, 0, stream>>>(
                Vb2, 960, 784L * 3840, 3840, Sb, 960, (long)C * 3840, 3840,
                QT, (long)NT * C, 784L * C, C,
                nullptr, (const float*)nullptr, 784, C, 960, 1.f, 0, nullptr);
        ctx_sum_kernel<<<(int)(((long)NT * C) / 1024), 256, 0, stream>>>(
            QT, cx2 + co[i], (long)NT * C);
    }

    // ---- 5) grouped Wo-all: xb = emb + ctx @ Wo^T ----
    {
        G4 g;
        int cum = 0;
        for (int i = 0; i < 4; i++) {
            const int C = Cs[i];
            const long C2 = (long)C * C;
            g.A[i] = cx2 + co[i]; g.B[i] = (const bf16*)(wp + wb[i] + 4 * C2);
            g.Cv[i] = xball + co[i];
            g.bias[i] = nullptr; g.res[i] = emb[i];
            g.M[i] = NT; g.N[i] = C; g.K[i] = C;
            g.lda[i] = C; g.ldb[i] = C; g.ldc[i] = C;
            g.nbx[i] = (C >= 128) ? C / 128 : 1;
            g.cum[i] = cum; cum += g.nbx[i] * 26;
        }
        g.cum[4] = cum;
        mfma4g<bf16, float><<<cum, 256, 0, stream>>>(g, 0);
    }
    // ---- 6) grouped LN ----
    {
        LR4 a;
        for (int i = 0; i < 4; i++) {
            a.X[i] = xball + co[i]; a.g[i] = fng[i]; a.b[i] = fnb[i];
            a.Y[i] = cx3 + co[i]; a.C[i] = Cs[i];
        }
        ln_rows4_kernel<<<dim3(3136, 4), 256, 0, stream>>>(a);
    }
    // ---- 7) grouped FFN1: hid = gelu(lnx @ w1^T + b1) ----
    {
        G4 g;
        int cum = 0;
        for (int i = 0; i < 4; i++) {
            const int C = Cs[i];
            const long C2 = (long)C * C;
            g.A[i] = cx3 + co[i]; g.B[i] = (const bf16*)(wp + wb[i] + 5 * C2);
            g.Cv[i] = hid + ho[i];
            g.bias[i] = b1[i]; g.res[i] = nullptr;
            g.M[i] = NT; g.N[i] = 4 * C; g.K[i] = C;
            g.lda[i] = C; g.ldb[i] = C; g.ldc[i] = 4 * C;
            g.nbx[i] = 4 * C / 128;
            g.cum[i] = cum; cum += g.nbx[i] * 26;
        }
        g.cum[4] = cum;
        mfma4g<bf16, float><<<cum, 256, 0, stream>>>(g, 1);
    }
    // ---- 8) grouped FFN2: out = xb + hid @ w2^T + b2 (fp32) ----
    {
        G4 g;
        int cum = 0;
        for (int i = 0; i < 4; i++) {
            const int C = Cs[i];
            const long C2 = (long)C * C;
            g.A[i] = hid + ho[i]; g.B[i] = (const bf16*)(wp + wb[i] + 9 * C2);
            g.Cv[i] = out + ooff[i];
            g.bias[i] = b2[i]; g.res[i] = xball + co[i];
            g.M[i] = NT; g.N[i] = C; g.K[i] = 4 * C;
            g.lda[i] = 4 * C; g.ldb[i] = 4 * C; g.ldc[i] = C;
            g.nbx[i] = (C >= 128) ? C / 128 : 1;
            g.cum[i] = cum; cum += g.nbx[i] * 26;
        }
        g.cum[4] = cum;
        mfma4g<float, bf16><<<cum, 256, 0, stream>>>(g, 0);
    }
}

// Round 10
// 632.294 us; speedup vs baseline: 1.4500x; 1.1411x over previous
//
#include <hip/hip_runtime.h>
#include <hip/hip_bf16.h>

// Block_ViT on MI355X — round 22: grouped ATTENTION phase (R20's dispatch-
// granularity win applied to the remaining 20 small launches):
//   Qproj512 -> S512 -> QprojRest(GZ,1) -> SRest(GZ,1,+stats) ->
//   softmaxAll(1) -> PVAll(GZ,1, 896 blk) -> ctxsumAll(1)
// mfmaGZ = mfma4 with 4-group descriptor + z decode + K-tail/pads. mfma2
// removed (C=64 via masked grouped paths). 24 -> 14 dispatches total.
// ws overlays re-derived, peak 99.6MB < 102MB: wkv/ea under QTpool/S512,
// cxall under SRest, tmp-all & hid under KT, cx2/xball/cx3 under Vb2.
// mfma8kv / mfma4 / mfma4g / ln kernels unchanged from R21/R20.
// B=4, N=784, H=4, Cs={64,128,256,512}, KV=960, NT=3136. fp32 in/out.

using bf16 = __hip_bfloat16;
typedef __attribute__((ext_vector_type(8))) short short8;   // 8 bf16 (4 VGPRs)
typedef __attribute__((ext_vector_type(4))) float f32x4;    // MFMA acc

__device__ inline float bf2f(unsigned short u) {
    return __uint_as_float(((unsigned int)u) << 16);
}
__device__ inline unsigned short f2b(float f) {            // RTNE fp32->bf16
    unsigned int u = __float_as_uint(f);
    return (unsigned short)((u + 0x7fffu + ((u >> 16) & 1u)) >> 16);
}
__device__ inline float ld1f(const float* p) { return *p; }
__device__ inline float ld1f(const bf16* p) { return bf2f(*(const unsigned short*)p); }
__device__ inline void st1(float* p, float v) { *p = v; }
__device__ inline void st1(bf16* p, float v) { *((unsigned short*)p) = f2b(v); }
__device__ inline float4 ld4f(const bf16* p) {
    ushort4 u = *(const ushort4*)p;
    return make_float4(bf2f(u.x), bf2f(u.y), bf2f(u.z), bf2f(u.w));
}

// async global->LDS, 16 B per lane; LDS dest = wave-uniform base + lane*16
__device__ __forceinline__ void cp16(const void* g, void* l) {
    __builtin_amdgcn_global_load_lds(
        (const __attribute__((address_space(1))) void*)g,
        (__attribute__((address_space(3))) void*)l, 16, 0, 0);
}

// ---- block reductions (256 threads = 4 waves) ----
__device__ inline float blockSum256(float v, float* red) {
    #pragma unroll
    for (int o = 32; o > 0; o >>= 1) v += __shfl_down(v, o);
    int t = threadIdx.x;
    if ((t & 63) == 0) red[t >> 6] = v;
    __syncthreads();
    float r = red[0] + red[1] + red[2] + red[3];
    __syncthreads();
    return r;
}
__device__ inline float blockMax256(float v, float* red) {
    #pragma unroll
    for (int o = 32; o > 0; o >>= 1) v = fmaxf(v, __shfl_down(v, o));
    int t = threadIdx.x;
    if ((t & 63) == 0) red[t >> 6] = v;
    __syncthreads();
    float r = fmaxf(fmaxf(red[0], red[1]), fmaxf(red[2], red[3]));
    __syncthreads();
    return r;
}

// ---- fp32 -> bf16 conversion of ALL weights (18 segments) + stat zeroing ----
struct CvtN {
    const float* s[18];
    unsigned short* d[18];
    long n[18];
    float* z;             // zero 128 floats (4 branches x 32 IN stats)
};
__global__ __launch_bounds__(256)
void cvtn_kernel(CvtN a) {
    if (a.z && blockIdx.x == 0 && threadIdx.x < 128) a.z[threadIdx.x] = 0.f;
    long tid = (long)blockIdx.x * 256 + threadIdx.x;
    long stride = (long)gridDim.x * 256;
    for (int g = 0; g < 18; g++) {
        const float* s = a.s[g];
        unsigned short* d = a.d[g];
        long n = a.n[g];
        for (long i = tid * 4; i < n; i += stride * 4) {
            float4 v = *(const float4*)(s + i);
            *(ushort4*)(d + i) = make_ushort4(f2b(v.x), f2b(v.y), f2b(v.z), f2b(v.w));
        }
    }
}

// ==== mfma8kv: fused K+V projection, 256x256 tile, 8 waves, BK=64 (R21) ====
__global__ __launch_bounds__(512, 2)
void mfma8kv(const bf16* __restrict__ A, const bf16* __restrict__ B,
             bf16* __restrict__ KT, bf16* __restrict__ V) {
    __shared__ short Asl[2][2][256][32];
    __shared__ short Bsl[2][2][256][32];
    const int M = 3136, lda = 960, ldb = 960;
    int orig = (int)blockIdx.y * 32 + (int)blockIdx.x;
    int c = orig & 7, r2 = orig >> 3;
    int bx = (c & 3) * 8 + (r2 & 7);
    int by = (c >> 2) * 7 + (r2 >> 3);
    int m0 = by * 256, n0 = bx * 256;
    if (m0 >= M || n0 >= 7680) return;
    int t = threadIdx.x, lane = t & 63, wv = t >> 6;
    int col = lane & 15, quad = lane >> 4;
    int wm = wv >> 2, wn = wv & 3;
    f32x4 acc[8][4];
    #pragma unroll
    for (int i = 0; i < 8; i++)
        #pragma unroll
        for (int j = 0; j < 4; j++) acc[i][j] = (f32x4){0.f, 0.f, 0.f, 0.f};

    int srow = lane >> 2;
    int scol = ((lane & 3) ^ ((lane >> 3) & 3)) << 3;
    int rslot = (quad ^ ((col >> 1) & 3)) << 3;

    auto stageA = [&](int s2, int kt, int kh) {
        int k0 = kt * 64 + kh * 32;
        #pragma unroll
        for (int r = 0; r < 2; r++) {
            int R0 = (r * 8 + wv) * 16;
            cp16(A + (long)(m0 + R0 + srow) * lda + k0 + scol, &Asl[s2][kh][R0][0]);
        }
    };
    auto stageB = [&](int s2, int kt, int kh) {
        int k0 = kt * 64 + kh * 32;
        #pragma unroll
        for (int r = 0; r < 2; r++) {
            int R0 = (r * 8 + wv) * 16;
            cp16(B + (long)(n0 + R0 + srow) * ldb + k0 + scol, &Bsl[s2][kh][R0][0]);
        }
    };

    const int nk = 15;
    stageA(0, 0, 0); stageB(0, 0, 0); stageA(0, 0, 1); stageB(0, 0, 1);
    __syncthreads();

    for (int kt = 0; kt < nk; kt++) {
        int cur = kt & 1, nxt = cur ^ 1;
        bool st = (kt + 1 < nk);
        short8 af[8], bf8[4];
        #pragma unroll
        for (int ni = 0; ni < 4; ni++)
            bf8[ni] = *(const short8*)&Bsl[cur][0][wn * 64 + ni * 16 + col][rslot];
        #pragma unroll
        for (int mi = 0; mi < 4; mi++)
            af[mi] = *(const short8*)&Asl[cur][0][wm * 128 + mi * 16 + col][rslot];
        if (st) stageA(nxt, kt + 1, 0);
        __builtin_amdgcn_s_barrier();
        asm volatile("s_waitcnt lgkmcnt(0)" ::: "memory");
        __builtin_amdgcn_sched_barrier(0);
        __builtin_amdgcn_s_setprio(1);
        #pragma unroll
        for (int mi = 0; mi < 4; mi++)
            #pragma unroll
            for (int ni = 0; ni < 4; ni++)
                acc[mi][ni] = __builtin_amdgcn_mfma_f32_16x16x32_bf16(
                    af[mi], bf8[ni], acc[mi][ni], 0, 0, 0);
        __builtin_amdgcn_s_setprio(0);
        __builtin_amdgcn_s_barrier();
        #pragma unroll
        for (int mi = 4; mi < 8; mi++)
            af[mi] = *(const short8*)&Asl[cur][0][wm * 128 + mi * 16 + col][rslot];
        if (st) stageB(nxt, kt + 1, 0);
        __builtin_amdgcn_s_barrier();
        asm volatile("s_waitcnt lgkmcnt(0)" ::: "memory");
        __builtin_amdgcn_sched_barrier(0);
        __builtin_amdgcn_s_setprio(1);
        #pragma unroll
        for (int mi = 4; mi < 8; mi++)
            #pragma unroll
            for (int ni = 0; ni < 4; ni++)
                acc[mi][ni] = __builtin_amdgcn_mfma_f32_16x16x32_bf16(
                    af[mi], bf8[ni], acc[mi][ni], 0, 0, 0);
        __builtin_amdgcn_s_setprio(0);
        if (st) asm volatile("s_waitcnt vmcnt(4)" ::: "memory");
        else    asm volatile("s_waitcnt vmcnt(0)" ::: "memory");
        __builtin_amdgcn_s_barrier();
        #pragma unroll
        for (int ni = 0; ni < 4; ni++)
            bf8[ni] = *(const short8*)&Bsl[cur][1][wn * 64 + ni * 16 + col][rslot];
        #pragma unroll
        for (int mi = 0; mi < 4; mi++)
            af[mi] = *(const short8*)&Asl[cur][1][wm * 128 + mi * 16 + col][rslot];
        if (st) stageA(nxt, kt + 1, 1);
        __builtin_amdgcn_s_barrier();
        asm volatile("s_waitcnt lgkmcnt(0)" ::: "memory");
        __builtin_amdgcn_sched_barrier(0);
        __builtin_amdgcn_s_setprio(1);
        #pragma unroll
        for (int mi = 0; mi < 4; mi++)
            #pragma unroll
            for (int ni = 0; ni < 4; ni++)
                acc[mi][ni] = __builtin_amdgcn_mfma_f32_16x16x32_bf16(
                    af[mi], bf8[ni], acc[mi][ni], 0, 0, 0);
        __builtin_amdgcn_s_setprio(0);
        __builtin_amdgcn_s_barrier();
        #pragma unroll
        for (int mi = 4; mi < 8; mi++)
            af[mi] = *(const short8*)&Asl[cur][1][wm * 128 + mi * 16 + col][rslot];
        if (st) stageB(nxt, kt + 1, 1);
        __builtin_amdgcn_s_barrier();
        asm volatile("s_waitcnt lgkmcnt(0)" ::: "memory");
        __builtin_amdgcn_sched_barrier(0);
        __builtin_amdgcn_s_setprio(1);
        #pragma unroll
        for (int mi = 4; mi < 8; mi++)
            #pragma unroll
            for (int ni = 0; ni < 4; ni++)
                acc[mi][ni] = __builtin_amdgcn_mfma_f32_16x16x32_bf16(
                    af[mi], bf8[ni], acc[mi][ni], 0, 0, 0);
        __builtin_amdgcn_s_setprio(0);
        if (st) asm volatile("s_waitcnt vmcnt(4)" ::: "memory");
        __builtin_amdgcn_s_barrier();
    }
    #pragma unroll
    for (int mi = 0; mi < 8; mi++) {
        int gmB = m0 + wm * 128 + mi * 16 + quad * 4;
        #pragma unroll
        for (int ni = 0; ni < 4; ni++) {
            int gn = n0 + wn * 64 + ni * 16 + col;
            if (gn < 3840) {
                if (gmB < M) {
                    ushort4 w = make_ushort4(f2b(acc[mi][ni][0]), f2b(acc[mi][ni][1]),
                                             f2b(acc[mi][ni][2]), f2b(acc[mi][ni][3]));
                    *(ushort4*)((unsigned short*)KT + (long)gn * M + gmB) = w;
                }
            } else {
                int vn = gn - 3840;
                #pragma unroll
                for (int r = 0; r < 4; r++) {
                    int gm = gmB + r;
                    if (gm < M) st1(V + (long)gm * 3840 + vn, acc[mi][ni][r]);
                }
            }
        }
    }
}

// ==== mfma4: 128x128, 4 waves, BK=32, 3 LDS slots (R19, unchanged) ====
template <class CT, class RT, bool TO>
__global__ __launch_bounds__(256, 3)
void mfma4(const bf16* __restrict__ A, long Ah, long Ab, int lda,
           const bf16* __restrict__ B, long Bh, long Bb, int ldb,
           CT* __restrict__ Cp, long Ch, long Cb, int ldc,
           const float* __restrict__ bias, const RT* __restrict__ res,
           int M, int N, int K, int Mpad, int Npad, int qx, int hy,
           float alpha, int dogelu, float* __restrict__ stat) {
    __shared__ short Asl[3][128][32];
    __shared__ short Bsl[3][128][32];
    int gx = gridDim.x, gy = gridDim.y;
    int orig = ((int)blockIdx.z * gy + (int)blockIdx.y) * gx + (int)blockIdx.x;
    int bx, by, bz;
    if (qx) {
        int c = orig & 7, r2 = orig >> 3;
        bx = (c & 3) * qx + r2 % qx;
        by = (c >> 2) * hy + r2 / qx;
        bz = 0;
    } else {
        int nxy = gx * gy, nwg = nxy * (int)gridDim.z;
        int q = nwg >> 3, r8 = nwg & 7;
        int xcd = orig & 7, pos = orig >> 3;
        int wgid = (xcd < r8 ? xcd * (q + 1) : r8 * (q + 1) + (xcd - r8) * q) + pos;
        bz = wgid / nxy;
        int rem = wgid - bz * nxy;
        by = rem / gx; bx = rem - by * gx;
    }
    int z = bz;
    A += (long)(z & 3) * Ah + (long)(z >> 2) * Ab;
    B += (long)(z & 3) * Bh + (long)(z >> 2) * Bb;
    Cp += (long)(z & 3) * Ch + (long)(z >> 2) * Cb;
    int m0 = by * 128, n0 = bx * 128;
    int t = threadIdx.x, lane = t & 63, wv = t >> 6;
    int col = lane & 15, quad = lane >> 4;
    int wm = wv >> 1, wn = wv & 1;
    f32x4 acc[4][4];
    #pragma unroll
    for (int i = 0; i < 4; i++)
        #pragma unroll
        for (int j = 0; j < 4; j++) acc[i][j] = (f32x4){0.f, 0.f, 0.f, 0.f};

    const bool fA = (m0 + 128 <= Mpad);
    const bool fB = (n0 + 128 <= Npad);
    int srow = lane >> 2;
    int scol = ((lane & 3) ^ ((lane >> 3) & 3)) << 3;
    int rslot = (quad ^ ((col >> 1) & 3)) << 3;

    auto stageA = [&](int s3, int kt) {
        int k0 = kt * 32;
        if (fA && k0 + 32 <= K) {
            #pragma unroll
            for (int r = 0; r < 2; r++) {
                int R0 = (r * 4 + wv) * 16;
                cp16(A + (long)(m0 + R0 + srow) * lda + k0 + scol, &Asl[s3][R0][0]);
            }
        } else {
            #pragma unroll
            for (int r = 0; r < 2; r++) {
                int idx = r * 256 + t;
                int row = idx >> 2, sl = idx & 3;
                int f2 = (row >> 1) & 3;
                short8 v = {};
                if (m0 + row < M && k0 + sl * 8 < K)
                    v = *(const short8*)(A + (long)(m0 + row) * lda + k0 + sl * 8);
                *(short8*)&Asl[s3][row][(sl ^ f2) * 8] = v;
            }
            asm volatile("s_waitcnt lgkmcnt(0)" ::: "memory");
        }
    };
    auto stageB = [&](int s3, int kt) {
        int k0 = kt * 32;
        if (fB && k0 + 32 <= K) {
            #pragma unroll
            for (int r = 0; r < 2; r++) {
                int R0 = (r * 4 + wv) * 16;
                cp16(B + (long)(n0 + R0 + srow) * ldb + k0 + scol, &Bsl[s3][R0][0]);
            }
        } else {
            #pragma unroll
            for (int r = 0; r < 2; r++) {
                int idx = r * 256 + t;
                int row = idx >> 2, sl = idx & 3;
                int f2 = (row >> 1) & 3;
                short8 v = {};
                if (n0 + row < N && k0 + sl * 8 < K)
                    v = *(const short8*)(B + (long)(n0 + row) * ldb + k0 + sl * 8);
                *(short8*)&Bsl[s3][row][(sl ^ f2) * 8] = v;
            }
            asm volatile("s_waitcnt lgkmcnt(0)" ::: "memory");
        }
    };

    int nk = (K + 31) >> 5;
    stageA(0, 0); stageB(0, 0);
    stageA(1, 1); stageB(1, 1);
    __syncthreads();

    for (int kt = 0; kt < nk; kt++) {
        int cur = kt % 3;
        short8 af[4], bf4[4];
        #pragma unroll
        for (int mi = 0; mi < 4; mi++)
            af[mi] = *(const short8*)&Asl[cur][wm * 64 + mi * 16 + col][rslot];
        #pragma unroll
        for (int ni = 0; ni < 4; ni++)
            bf4[ni] = *(const short8*)&Bsl[cur][wn * 64 + ni * 16 + col][rslot];
        int pend = 0;
        if (kt + 2 < nk) {
            int s3 = (kt + 2) % 3;
            stageA(s3, kt + 2); stageB(s3, kt + 2);
            if ((kt + 2) * 32 + 32 <= K) pend = (fA ? 2 : 0) + (fB ? 2 : 0);
        }
        __builtin_amdgcn_s_barrier();
        asm volatile("s_waitcnt lgkmcnt(0)" ::: "memory");
        __builtin_amdgcn_sched_barrier(0);
        __builtin_amdgcn_s_setprio(1);
        #pragma unroll
        for (int mi = 0; mi < 4; mi++)
            #pragma unroll
            for (int ni = 0; ni < 4; ni++)
                acc[mi][ni] = __builtin_amdgcn_mfma_f32_16x16x32_bf16(
                    af[mi], bf4[ni], acc[mi][ni], 0, 0, 0);
        __builtin_amdgcn_s_setprio(0);
        if (kt + 1 < nk) {
            if (pend == 4)      asm volatile("s_waitcnt vmcnt(4)" ::: "memory");
            else if (pend == 2) asm volatile("s_waitcnt vmcnt(2)" ::: "memory");
            else                asm volatile("s_waitcnt vmcnt(0)" ::: "memory");
            __builtin_amdgcn_s_barrier();
        }
    }
    float psum = 0.f, psq = 0.f;
    #pragma unroll
    for (int mi = 0; mi < 4; mi++) {
        int gmB = m0 + wm * 64 + mi * 16 + quad * 4;
        #pragma unroll
        for (int ni = 0; ni < 4; ni++) {
            int gn = n0 + wn * 64 + ni * 16 + col;
            if constexpr (TO) {
                if (gmB < M && gn < N) {
                    ushort4 w = make_ushort4(f2b(acc[mi][ni][0] * alpha),
                                             f2b(acc[mi][ni][1] * alpha),
                                             f2b(acc[mi][ni][2] * alpha),
                                             f2b(acc[mi][ni][3] * alpha));
                    *(ushort4*)((unsigned short*)Cp + (long)gn * ldc + gmB) = w;
                }
            } else {
                if (gn < N) {
                    float bz2 = bias ? bias[gn] : 0.f;
                    #pragma unroll
                    for (int r = 0; r < 4; r++) {
                        int gm = gmB + r;
                        if (gm < M) {
                            float v = acc[mi][ni][r] * alpha + bz2;
                            if (dogelu) v = 0.5f * v * (1.f + erff(v * 0.70710678118f));
                            if (res) v += ld1f(res + (long)gm * ldc + gn);
                            st1(Cp + (long)gm * ldc + gn, v);
                            psum += v; psq += v * v;
                        }
                    }
                }
            }
        }
    }
    if (stat) {
        __syncthreads();
        #pragma unroll
        for (int o = 32; o > 0; o >>= 1) {
            psum += __shfl_down(psum, o);
            psq  += __shfl_down(psq, o);
        }
        float* red = (float*)Asl;
        if ((t & 63) == 0) { red[wv] = psum; red[4 + wv] = psq; }
        __syncthreads();
        if (t == 0) {
            atomicAdd(&stat[2 * z],     red[0] + red[1] + red[2] + red[3]);
            atomicAdd(&stat[2 * z + 1], red[4] + red[5] + red[6] + red[7]);
        }
    }
}

// ==== mfmaGZ: grouped (<=4) z-batched 128x128 GEMM with tails (attention) ====
// Per group: C[z] = alpha * A[z] @ B[z]^T; z-offsets (z&3)*Xh + (z>>2)*Xb.
// TO: transposed bf16 store. stat: fused IN sum/sumsq atomicAdd per z.
struct GZ {
    const bf16* A[4]; const bf16* B[4]; bf16* C[4];
    long Ah[4], Ab[4], Bh[4], Bb[4], Ch[4], Cb[4];
    int lda[4], ldb[4], ldc[4], M[4], N[4], K[4], Mpad[4], Npad[4], nbx[4], nby[4];
    float alpha[4];
    float* stat[4];
    int cum[5];
};
template <bool TO>
__global__ __launch_bounds__(256, 3)
void mfmaGZ(GZ g) {
    __shared__ short Asl[3][128][32];
    __shared__ short Bsl[3][128][32];
    int nwg = gridDim.x;
    int orig = blockIdx.x;
    int q = nwg >> 3, r8 = nwg & 7;
    int xcd = orig & 7, pos = orig >> 3;
    int wgid = (xcd < r8 ? xcd * (q + 1) : r8 * (q + 1) + (xcd - r8) * q) + pos;
    int gi = 0;
    if (wgid >= g.cum[1]) gi = 1;
    if (wgid >= g.cum[2]) gi = 2;
    if (wgid >= g.cum[3]) gi = 3;
    int local = wgid - g.cum[gi];
    int nbx = g.nbx[gi], nby = g.nby[gi];
    int z = local / (nbx * nby);
    int rem = local - z * nbx * nby;
    int by = rem / nbx, bx = rem - by * nbx;
    const bf16* A = g.A[gi] + (long)(z & 3) * g.Ah[gi] + (long)(z >> 2) * g.Ab[gi];
    const bf16* B = g.B[gi] + (long)(z & 3) * g.Bh[gi] + (long)(z >> 2) * g.Bb[gi];
    bf16* Cp = g.C[gi] + (long)(z & 3) * g.Ch[gi] + (long)(z >> 2) * g.Cb[gi];
    int lda = g.lda[gi], ldb = g.ldb[gi], ldc = g.ldc[gi];
    int M = g.M[gi], N = g.N[gi], K = g.K[gi];
    int Mpad = g.Mpad[gi], Npad = g.Npad[gi];
    float alpha = g.alpha[gi];
    float* stat = g.stat[gi];

    int m0 = by * 128, n0 = bx * 128;
    int t = threadIdx.x, lane = t & 63, wv = t >> 6;
    int col = lane & 15, quad = lane >> 4;
    int wm = wv >> 1, wn = wv & 1;
    f32x4 acc[4][4];
    #pragma unroll
    for (int i = 0; i < 4; i++)
        #pragma unroll
        for (int j = 0; j < 4; j++) acc[i][j] = (f32x4){0.f, 0.f, 0.f, 0.f};

    const bool fA = (m0 + 128 <= Mpad);
    const bool fB = (n0 + 128 <= Npad);
    int srow = lane >> 2;
    int scol = ((lane & 3) ^ ((lane >> 3) & 3)) << 3;
    int rslot = (quad ^ ((col >> 1) & 3)) << 3;

    auto stageA = [&](int s3, int kt) {
        int k0 = kt * 32;
        if (fA && k0 + 32 <= K) {
            #pragma unroll
            for (int r = 0; r < 2; r++) {
                int R0 = (r * 4 + wv) * 16;
                cp16(A + (long)(m0 + R0 + srow) * lda + k0 + scol, &Asl[s3][R0][0]);
            }
        } else {
            #pragma unroll
            for (int r = 0; r < 2; r++) {
                int idx = r * 256 + t;
                int row = idx >> 2, sl = idx & 3;
                int f2 = (row >> 1) & 3;
                short8 v = {};
                if (m0 + row < M && k0 + sl * 8 < K)
                    v = *(const short8*)(A + (long)(m0 + row) * lda + k0 + sl * 8);
                *(short8*)&Asl[s3][row][(sl ^ f2) * 8] = v;
            }
            asm volatile("s_waitcnt lgkmcnt(0)" ::: "memory");
        }
    };
    auto stageB = [&](int s3, int kt) {
        int k0 = kt * 32;
        if (fB && k0 + 32 <= K) {
            #pragma unroll
            for (int r = 0; r < 2; r++) {
                int R0 = (r * 4 + wv) * 16;
                cp16(B + (long)(n0 + R0 + srow) * ldb + k0 + scol, &Bsl[s3][R0][0]);
            }
        } else {
            #pragma unroll
            for (int r = 0; r < 2; r++) {
                int idx = r * 256 + t;
                int row = idx >> 2, sl = idx & 3;
                int f2 = (row >> 1) & 3;
                short8 v = {};
                if (n0 + row < N && k0 + sl * 8 < K)
                    v = *(const short8*)(B + (long)(n0 + row) * ldb + k0 + sl * 8);
                *(short8*)&Bsl[s3][row][(sl ^ f2) * 8] = v;
            }
            asm volatile("s_waitcnt lgkmcnt(0)" ::: "memory");
        }
    };

    int nk = (K + 31) >> 5;
    stageA(0, 0); stageB(0, 0);
    stageA(1, 1); stageB(1, 1);
    __syncthreads();

    for (int kt = 0; kt < nk; kt++) {
        int cur = kt % 3;
        short8 af[4], bf4[4];
        #pragma unroll
        for (int mi = 0; mi < 4; mi++)
            af[mi] = *(const short8*)&Asl[cur][wm * 64 + mi * 16 + col][rslot];
        #pragma unroll
        for (int ni = 0; ni < 4; ni++)
            bf4[ni] = *(const short8*)&Bsl[cur][wn * 64 + ni * 16 + col][rslot];
        int pend = 0;
        if (kt + 2 < nk) {
            int s3 = (kt + 2) % 3;
            stageA(s3, kt + 2); stageB(s3, kt + 2);
            if ((kt + 2) * 32 + 32 <= K) pend = (fA ? 2 : 0) + (fB ? 2 : 0);
        }
        __builtin_amdgcn_s_barrier();
        asm volatile("s_waitcnt lgkmcnt(0)" ::: "memory");
        __builtin_amdgcn_sched_barrier(0);
        __builtin_amdgcn_s_setprio(1);
        #pragma unroll
        for (int mi = 0; mi < 4; mi++)
            #pragma unroll
            for (int ni = 0; ni < 4; ni++)
                acc[mi][ni] = __builtin_amdgcn_mfma_f32_16x16x32_bf16(
                    af[mi], bf4[ni], acc[mi][ni], 0, 0, 0);
        __builtin_amdgcn_s_setprio(0);
        if (kt + 1 < nk) {
            if (pend == 4)      asm volatile("s_waitcnt vmcnt(4)" ::: "memory");
            else if (pend == 2) asm volatile("s_waitcnt vmcnt(2)" ::: "memory");
            else                asm volatile("s_waitcnt vmcnt(0)" ::: "memory");
            __builtin_amdgcn_s_barrier();
        }
    }
    float psum = 0.f, psq = 0.f;
    #pragma unroll
    for (int mi = 0; mi < 4; mi++) {
        int gmB = m0 + wm * 64 + mi * 16 + quad * 4;
        #pragma unroll
        for (int ni = 0; ni < 4; ni++) {
            int gn = n0 + wn * 64 + ni * 16 + col;
            if constexpr (TO) {
                if (gmB < M && gn < N) {
                    ushort4 w = make_ushort4(f2b(acc[mi][ni][0] * alpha),
                                             f2b(acc[mi][ni][1] * alpha),
                                             f2b(acc[mi][ni][2] * alpha),
                                             f2b(acc[mi][ni][3] * alpha));
                    *(ushort4*)((unsigned short*)Cp + (long)gn * ldc + gmB) = w;
                }
            } else {
                if (gn < N) {
                    #pragma unroll
                    for (int r = 0; r < 4; r++) {
                        int gm = gmB + r;
                        if (gm < M) {
                            float v = acc[mi][ni][r] * alpha;
                            st1(Cp + (long)gm * ldc + gn, v);
                            psum += v; psq += v * v;
                        }
                    }
                }
            }
        }
    }
    if (stat) {
        __syncthreads();
        #pragma unroll
        for (int o = 32; o > 0; o >>= 1) {
            psum += __shfl_down(psum, o);
            psq  += __shfl_down(psq, o);
        }
        float* red = (float*)Asl;
        if ((t & 63) == 0) { red[wv] = psum; red[4 + wv] = psq; }
        __syncthreads();
        if (t == 0) {
            atomicAdd(&stat[2 * z],     red[0] + red[1] + red[2] + red[3]);
            atomicAdd(&stat[2 * z + 1], red[4] + red[5] + red[6] + red[7]);
        }
    }
}

// ==== mfma4g: grouped (4-problem) 128x128 GEMM, pure fast path (R20) ====
struct G4 {
    const bf16* A[4]; const bf16* B[4]; void* Cv[4];
    const float* bias[4]; const void* res[4];
    int M[4], N[4], K[4], lda[4], ldb[4], ldc[4], nbx[4];
    int cum[5];
};
template <class CT, class RT>
__global__ __launch_bounds__(256, 3)
void mfma4g(G4 gp, int dogelu) {
    __shared__ short Asl[3][128][32];
    __shared__ short Bsl[3][128][32];
    int nwg = gridDim.x;
    int orig = blockIdx.x;
    int q = nwg >> 3, r8 = nwg & 7;
    int xcd = orig & 7, pos = orig >> 3;
    int wgid = (xcd < r8 ? xcd * (q + 1) : r8 * (q + 1) + (xcd - r8) * q) + pos;
    int gi = 0;
    if (wgid >= gp.cum[1]) gi = 1;
    if (wgid >= gp.cum[2]) gi = 2;
    if (wgid >= gp.cum[3]) gi = 3;
    int local = wgid - gp.cum[gi];
    int nbx = gp.nbx[gi];
    int by = local / nbx, bx = local - by * nbx;
    const bf16* A = gp.A[gi];
    const bf16* B = gp.B[gi];
    CT* Cp = (CT*)gp.Cv[gi];
    const float* bias = gp.bias[gi];
    const RT* res = (const RT*)gp.res[gi];
    int M = gp.M[gi], N = gp.N[gi], K = gp.K[gi];
    int lda = gp.lda[gi], ldb = gp.ldb[gi], ldc = gp.ldc[gi];
    int m0 = by * 128, n0 = bx * 128;
    int t = threadIdx.x, lane = t & 63, wv = t >> 6;
    int col = lane & 15, quad = lane >> 4;
    int wm = wv >> 1, wn = wv & 1;
    f32x4 acc[4][4];
    #pragma unroll
    for (int i = 0; i < 4; i++)
        #pragma unroll
        for (int j = 0; j < 4; j++) acc[i][j] = (f32x4){0.f, 0.f, 0.f, 0.f};

    int srow = lane >> 2;
    int scol = ((lane & 3) ^ ((lane >> 3) & 3)) << 3;
    int rslot = (quad ^ ((col >> 1) & 3)) << 3;

    auto stageA = [&](int s3, int kt) {
        int k0 = kt * 32;
        #pragma unroll
        for (int r = 0; r < 2; r++) {
            int R0 = (r * 4 + wv) * 16;
            cp16(A + (long)(m0 + R0 + srow) * lda + k0 + scol, &Asl[s3][R0][0]);
        }
    };
    auto stageB = [&](int s3, int kt) {
        int k0 = kt * 32;
        #pragma unroll
        for (int r = 0; r < 2; r++) {
            int R0 = (r * 4 + wv) * 16;
            cp16(B + (long)(n0 + R0 + srow) * ldb + k0 + scol, &Bsl[s3][R0][0]);
        }
    };

    int nk = K >> 5;
    stageA(0, 0); stageB(0, 0);
    stageA(1, 1); stageB(1, 1);
    __syncthreads();

    for (int kt = 0; kt < nk; kt++) {
        int cur = kt % 3;
        short8 af[4], bf4[4];
        #pragma unroll
        for (int mi = 0; mi < 4; mi++)
            af[mi] = *(const short8*)&Asl[cur][wm * 64 + mi * 16 + col][rslot];
        #pragma unroll
        for (int ni = 0; ni < 4; ni++)
            bf4[ni] = *(const short8*)&Bsl[cur][wn * 64 + ni * 16 + col][rslot];
        bool st = (kt + 2 < nk);
        if (st) {
            int s3 = (kt + 2) % 3;
            stageA(s3, kt + 2); stageB(s3, kt + 2);
        }
        __builtin_amdgcn_s_barrier();
        asm volatile("s_waitcnt lgkmcnt(0)" ::: "memory");
        __builtin_amdgcn_sched_barrier(0);
        __builtin_amdgcn_s_setprio(1);
        #pragma unroll
        for (int mi = 0; mi < 4; mi++)
            #pragma unroll
            for (int ni = 0; ni < 4; ni++)
                acc[mi][ni] = __builtin_amdgcn_mfma_f32_16x16x32_bf16(
                    af[mi], bf4[ni], acc[mi][ni], 0, 0, 0);
        __builtin_amdgcn_s_setprio(0);
        if (kt + 1 < nk) {
            if (st) asm volatile("s_waitcnt vmcnt(4)" ::: "memory");
            else    asm volatile("s_waitcnt vmcnt(0)" ::: "memory");
            __builtin_amdgcn_s_barrier();
        }
    }
    #pragma unroll
    for (int mi = 0; mi < 4; mi++) {
        int gmB = m0 + wm * 64 + mi * 16 + quad * 4;
        #pragma unroll
        for (int ni = 0; ni < 4; ni++) {
            int gn = n0 + wn * 64 + ni * 16 + col;
            if (gn < N) {
                float bz2 = bias ? bias[gn] : 0.f;
                #pragma unroll
                for (int r = 0; r < 4; r++) {
                    int gm = gmB + r;
                    if (gm < M) {
                        float v = acc[mi][ni][r] + bz2;
                        if (dogelu) v = 0.5f * v * (1.f + erff(v * 0.70710678118f));
                        if (res) v += ld1f(res + (long)gm * ldc + gn);
                        st1(Cp + (long)gm * ldc + gn, v);
                    }
                }
            }
        }
    }
}

// ---- merged LayerNorms: concat-LN (ea) + 4 branch first-LNs ----
struct LNA {
    const float* e[4];
    const float* ag[4];
    const float* ab[4];
    const float* cg;
    const float* cbb;
    bf16* y[4];
    bf16* ea;
};
__global__ __launch_bounds__(256)
void ln_all_kernel(LNA a) {
    __shared__ float x[960];
    __shared__ float red[4];
    long row = blockIdx.x;
    int t = threadIdx.x;
    const int off[5] = {0, 64, 192, 448, 960};
    {
        const float* p1 = a.e[0] + row * 64;
        const float* p2 = a.e[1] + row * 128;
        const float* p3 = a.e[2] + row * 256;
        const float* p4 = a.e[3] + row * 512;
        if (t < 64) x[t] = p1[t];
        for (int i = t; i < 128; i += 256) x[64 + i]  = p2[i];
        for (int i = t; i < 256; i += 256) x[192 + i] = p3[i];
        for (int i = t; i < 512; i += 256) x[448 + i] = p4[i];
    }
    __syncthreads();
    float ssum[4], ssq[4];
    #pragma unroll
    for (int br = 0; br < 4; br++) {
        float s = 0.f, q = 0.f;
        for (int i = off[br] + t; i < off[br + 1]; i += 256) {
            float v = x[i]; s += v; q += v * v;
        }
        ssum[br] = blockSum256(s, red);
        ssq[br]  = blockSum256(q, red);
    }
    float S1 = ssum[0] + ssum[1] + ssum[2] + ssum[3];
    float S2 = ssq[0] + ssq[1] + ssq[2] + ssq[3];
    float muA = S1 * (1.f / 960.f);
    float rA = rsqrtf(S2 * (1.f / 960.f) - muA * muA + 1e-6f);
    for (int i = t; i < 960; i += 256)
        st1(a.ea + row * 960 + i, (x[i] - muA) * rA * a.cg[i] + a.cbb[i]);
    #pragma unroll
    for (int br = 0; br < 4; br++) {
        int C = off[br + 1] - off[br];
        float mu = ssum[br] / C;
        float rr = rsqrtf(ssq[br] / C - mu * mu + 1e-6f);
        const float* g = a.ag[br];
        const float* b = a.ab[br];
        bf16* y = a.y[br] + row * C;
        for (int i = t; i < C; i += 256)
            st1(y + i, (x[off[br] + i] - mu) * rr * g[i] + b[i]);
    }
}

// ---- grouped row LayerNorm: grid (3136, 4) ----
struct LR4 {
    const bf16* X[4];
    const float* g[4];
    const float* b[4];
    bf16* Y[4];
    int C[4];
};
__global__ __launch_bounds__(256)
void ln_rows4_kernel(LR4 a) {
    __shared__ float x[512];
    __shared__ float red[4];
    int br = blockIdx.y;
    long row = blockIdx.x;
    int C = a.C[br];
    int t = threadIdx.x;
    const bf16* xr = a.X[br] + row * C;
    float s = 0.f, q = 0.f;
    for (int i = t; i < C; i += 256) { float v = ld1f(xr + i); x[i] = v; s += v; q += v * v; }
    float S1 = blockSum256(s, red), S2 = blockSum256(q, red);
    float mu = S1 / C;
    float r = rsqrtf(S2 / C - mu * mu + 1e-6f);
    const float* g = a.g[br];
    const float* b = a.b[br];
    bf16* y = a.Y[br] + row * C;
    for (int i = t; i < C; i += 256)
        st1(y + i, (x[i] - mu) * r * g[i] + b[i]);
}

// ---- grouped softmax over last dim (960); rstd from fused stats ----
struct SMX {
    bf16* S[4];
    const float* stat[4];
    int C[4];
    int cum[5];
};
__global__ __launch_bounds__(256)
void softmax_all_kernel(SMX a) {
    __shared__ float x[960];
    __shared__ float red[4];
    int rid = blockIdx.x;
    int gi = 0;
    if (rid >= a.cum[1]) gi = 1;
    if (rid >= a.cum[2]) gi = 2;
    if (rid >= a.cum[3]) gi = 3;
    int local = rid - a.cum[gi];
    int C = a.C[gi];
    int z = local / C;
    int d = local - z * C;
    int t = threadIdx.x;
    float n = 960.f * (float)C;
    float s0 = a.stat[gi][2 * z], q0 = a.stat[gi][2 * z + 1];
    float mu = s0 / n;
    float rs = rsqrtf(q0 / n - mu * mu + 1e-5f);
    int h = z & 3, b = z >> 2;
    bf16* row = a.S[gi] + (long)b * C * 3840 + (long)d * 3840 + h * 960;
    float mx = -3.4e38f;
    for (int i = t; i < 960; i += 256) {
        float v = ld1f(row + i) * rs; x[i] = v; mx = fmaxf(mx, v);
    }
    float M = blockMax256(mx, red);
    float s = 0.f;
    for (int i = t; i < 960; i += 256) { float e = __expf(x[i] - M); x[i] = e; s += e; }
    float Ssum = blockSum256(s, red);
    float inv = 1.f / Ssum;
    for (int i = t; i < 960; i += 256) st1(row + i, x[i] * inv);
}

// ---- grouped ctx head-sum: ctx[i] = 0.25*sum_h tmp[h][i] ----
struct CSX {
    const bf16* tmp[4];
    bf16* ctx[4];
    long NTC[4];
    int cum[5];
};
__global__ __launch_bounds__(256)
void ctxsum_all_kernel(CSX a) {
    int bid = blockIdx.x;
    int gi = 0;
    if (bid >= a.cum[1]) gi = 1;
    if (bid >= a.cum[2]) gi = 2;
    if (bid >= a.cum[3]) gi = 3;
    long local = bid - a.cum[gi];
    long NTC = a.NTC[gi];
    const bf16* tmp = a.tmp[gi];
    long i = (local * 256 + threadIdx.x) * 4;
    float4 p = ld4f(tmp + i);
    float4 b = ld4f(tmp + NTC + i);
    float4 c = ld4f(tmp + 2 * NTC + i);
    float4 d = ld4f(tmp + 3 * NTC + i);
    ushort4 o = make_ushort4(f2b((p.x + b.x + c.x + d.x) * 0.25f),
                             f2b((p.y + b.y + c.y + d.y) * 0.25f),
                             f2b((p.z + b.z + c.z + d.z) * 0.25f),
                             f2b((p.w + b.w + c.w + d.w) * 0.25f));
    *(ushort4*)(a.ctx[gi] + i) = o;
}

extern "C" void kernel_launch(void* const* d_in, const int* in_sizes, int n_in,
                              void* d_out, int out_size, void* d_ws, size_t ws_size,
                              hipStream_t stream) {
    (void)in_sizes; (void)n_in; (void)out_size; (void)ws_size;
    const int Cs[4] = {64, 128, 256, 512};
    const float *emb[4], *ang[4], *anb[4], *Wq[4], *Wo[4], *fng[4], *fnb[4], *w1[4], *b1[4], *w2[4], *b2[4];
    for (int i = 0; i < 4; i++) {
        const int base = i * 11;
        emb[i] = (const float*)d_in[base + 0];
        ang[i] = (const float*)d_in[base + 1];
        anb[i] = (const float*)d_in[base + 2];
        Wq[i]  = (const float*)d_in[base + 3];
        Wo[i]  = (const float*)d_in[base + 4];
        fng[i] = (const float*)d_in[base + 5];
        fnb[i] = (const float*)d_in[base + 6];
        w1[i]  = (const float*)d_in[base + 7];
        b1[i]  = (const float*)d_in[base + 8];
        w2[i]  = (const float*)d_in[base + 9];
        b2[i]  = (const float*)d_in[base + 10];
    }
    const float* anAg = (const float*)d_in[44];
    const float* anAb = (const float*)d_in[45];
    const float* Wk   = (const float*)d_in[46];
    const float* Wv   = (const float*)d_in[47];

    const int NT = 3136;
    char* wsb = (char*)d_ws;
    // ---- layout (bytes), peak 99.56MB < 102MB; overlays per phase comments ----
    unsigned short* wp = (unsigned short*)(wsb);          // 0..9,052,160
    float* statb = (float*)(wsb + 9052160);               // 128 floats
    bf16*  KT    = (bf16*)(wsb + 9053184);                // [3840][3136] 24.08M
    bf16*  tmpb  = KT;                                    // PV out (over KT)
    bf16*  hid   = KT;                                    // FFN hid (over tmp)
    bf16*  Vb2   = (bf16*)(wsb + 33137664);               // [3136][3840] 24.08M
    bf16*  cx2   = (bf16*)(wsb + 33137664);               // ctx (over Vb2, P7+)
    bf16*  xball = (bf16*)(wsb + 39158784);               // (over Vb2, P8+)
    bf16*  cx3   = (bf16*)(wsb + 45179904);               // (over Vb2, P9+)
    bf16*  QTp   = (bf16*)(wsb + 57222144);               // QT pool 12.85M
    bf16*  wkv   = (bf16*)(wsb + 57222144);               // [7680][960] early
    bf16*  S5    = (bf16*)(wsb + 70067200);               // S(C=512) 15.73M
    bf16*  ea    = (bf16*)(wsb + 71967744);               // early (inside S5)
    bf16*  SR    = (bf16*)(wsb + 85795840);               // S rest 13.76M
    bf16*  cxall = (bf16*)(wsb + 85795840);               // early (inside SR)

    const long wb[4]  = {0, 53248, 266240, 1118208};      // weight pool prefix
    const long co[4]  = {0, 200704, 602112, 1404928};     // [NT][C] offsets
    const long ho[4]  = {0, 802816, 2408448, 5619712};    // hid offsets
    const long qro[3] = {4816896, 3211264, 0};            // QTrest: i=0,1,2
    const long sro[3] = {5898240, 3932160, 0};            // SRest:  i=0,1,2
    const long tpo[4] = {11239424, 9633792, 6422528, 0};  // tmp:    i=0..3

    float* out = (float*)d_out;
    const float scale = 0.03227486121f;  // 1/sqrt(960)

    // ---- 1) all weights -> bf16 + zero stats ----
    {
        CvtN a;
        a.s[0] = Wk; a.d[0] = (unsigned short*)wkv;           a.n[0] = 3686400;
        a.s[1] = Wv; a.d[1] = (unsigned short*)wkv + 3686400; a.n[1] = 3686400;
        for (int i = 0; i < 4; i++) {
            const long C2 = (long)Cs[i] * Cs[i];
            a.s[2 + 4 * i] = Wq[i]; a.d[2 + 4 * i] = wp + wb[i];          a.n[2 + 4 * i] = 4 * C2;
            a.s[3 + 4 * i] = Wo[i]; a.d[3 + 4 * i] = wp + wb[i] + 4 * C2; a.n[3 + 4 * i] = C2;
            a.s[4 + 4 * i] = w1[i]; a.d[4 + 4 * i] = wp + wb[i] + 5 * C2; a.n[4 + 4 * i] = 4 * C2;
            a.s[5 + 4 * i] = w2[i]; a.d[5 + 4 * i] = wp + wb[i] + 9 * C2; a.n[5 + 4 * i] = 4 * C2;
        }
        a.z = statb;
        cvtn_kernel<<<1024, 256, 0, stream>>>(a);
    }
    // ---- 2) merged LayerNorms ----
    {
        LNA a;
        for (int i = 0; i < 4; i++) {
            a.e[i] = emb[i]; a.ag[i] = ang[i]; a.ab[i] = anb[i];
            a.y[i] = cxall + co[i];
        }
        a.cg = anAg; a.cbb = anAb; a.ea = ea;
        ln_all_kernel<<<3136, 256, 0, stream>>>(a);
    }
    // ---- 3) fused K+V projection ----
    mfma8kv<<<dim3(32, 14, 1), 512, 0, stream>>>(ea, wkv, KT, Vb2);

    // ---- 4a) Qproj C=512 -> QTp ----
    mfma4<bf16, float, true><<<dim3(4, 26, 4), 256, 0, stream>>>(
        cxall + co[3], 0, 0, 512, (const bf16*)(wp + wb[3]), 262144, 0, 512,
        QTp, 512L * NT, 0, NT,
        nullptr, (const float*)nullptr, NT, 512, 512, 3328, 512, 0, 0,
        1.f, 0, nullptr);
    // ---- 4b) S C=512 (+stats) -> S5 ----
    mfma4<bf16, float, false><<<dim3(8, 4, 16), 256, 0, stream>>>(
        QTp, 512L * NT, 784, NT, KT, 3010560, 784, NT,
        S5, 960, 512L * 3840, 3840,
        nullptr, (const float*)nullptr, 512, 960, 784, 512, 1024, 0, 0,
        scale, 0, statb + 32 * 3);
    // ---- 4c) Qproj rest (C=256,128,64) grouped -> QTp ----
    {
        GZ g;
        int cum = 0;
        const int ord[3] = {2, 1, 0};
        for (int j = 0; j < 3; j++) {
            int i = ord[j], C = Cs[i];
            g.A[j] = cxall + co[i]; g.Ah[j] = 0; g.Ab[j] = 0; g.lda[j] = C;
            g.B[j] = (const bf16*)(wp + wb[i]); g.Bh[j] = (long)C * C; g.Bb[j] = 0; g.ldb[j] = C;
            g.C[j] = QTp + qro[i]; g.Ch[j] = (long)C * NT; g.Cb[j] = 0; g.ldc[j] = NT;
            g.M[j] = NT; g.N[j] = C; g.K[j] = C;
            g.Mpad[j] = 3328; g.Npad[j] = (C >= 128) ? C : 64;
            g.nbx[j] = (C >= 128) ? C / 128 : 1; g.nby[j] = 26;
            g.alpha[j] = 1.f; g.stat[j] = nullptr;
            g.cum[j] = cum; cum += g.nbx[j] * 26 * 4;
        }
        g.cum[3] = cum; g.cum[4] = cum;
        mfmaGZ<true><<<cum, 256, 0, stream>>>(g);
    }
    // ---- 4d) S rest grouped (+stats) -> SR ----
    {
        GZ g;
        int cum = 0;
        const int ord[3] = {2, 1, 0};
        for (int j = 0; j < 3; j++) {
            int i = ord[j], C = Cs[i];
            g.A[j] = QTp + qro[i]; g.Ah[j] = (long)C * NT; g.Ab[j] = 784; g.lda[j] = NT;
            g.B[j] = KT; g.Bh[j] = 3010560; g.Bb[j] = 784; g.ldb[j] = NT;
            g.C[j] = SR + sro[i]; g.Ch[j] = 960; g.Cb[j] = (long)C * 3840; g.ldc[j] = 3840;
            g.M[j] = C; g.N[j] = 960; g.K[j] = 784;
            g.Mpad[j] = (C >= 128) ? C : 64; g.Npad[j] = 1024;
            g.nbx[j] = 8; g.nby[j] = (C >= 128) ? C / 128 : 1;
            g.alpha[j] = scale; g.stat[j] = statb + 32 * i;
            g.cum[j] = cum; cum += 8 * g.nby[j] * 16;
        }
        g.cum[3] = cum; g.cum[4] = cum;
        mfmaGZ<false><<<cum, 256, 0, stream>>>(g);
    }
    // ---- 5) softmax all branches ----
    {
        SMX a;
        const int ord[4] = {3, 2, 1, 0};
        int cum = 0;
        for (int j = 0; j < 4; j++) {
            int i = ord[j], C = Cs[i];
            a.S[j] = (i == 3) ? S5 : SR + sro[i];
            a.stat[j] = statb + 32 * i;
            a.C[j] = C;
            a.cum[j] = cum; cum += 16 * C;
        }
        a.cum[4] = cum;
        softmax_all_kernel<<<cum, 256, 0, stream>>>(a);
    }
    // ---- 6) PV all branches grouped -> tmpb (over KT) ----
    {
        GZ g;
        int cum = 0;
        const int ord[4] = {3, 2, 1, 0};
        for (int j = 0; j < 4; j++) {
            int i = ord[j], C = Cs[i];
            g.A[j] = Vb2; g.Ah[j] = 960; g.Ab[j] = 784L * 3840; g.lda[j] = 3840;
            g.B[j] = (i == 3) ? S5 : SR + sro[i];
            g.Bh[j] = 960; g.Bb[j] = (long)C * 3840; g.ldb[j] = 3840;
            g.C[j] = tmpb + tpo[i]; g.Ch[j] = (long)NT * C; g.Cb[j] = 784L * C; g.ldc[j] = C;
            g.M[j] = 784; g.N[j] = C; g.K[j] = 960;
            g.Mpad[j] = 896; g.Npad[j] = (C >= 128) ? C : 64;
            g.nbx[j] = (C >= 128) ? C / 128 : 1; g.nby[j] = 7;
            g.alpha[j] = 1.f; g.stat[j] = nullptr;
            g.cum[j] = cum; cum += g.nbx[j] * 7 * 16;
        }
        g.cum[4] = cum;
        mfmaGZ<false><<<cum, 256, 0, stream>>>(g);
    }
    // ---- 7) ctx head-sum all branches -> cx2 (over Vb2) ----
    {
        CSX a;
        int cum = 0;
        const int ord[4] = {3, 2, 1, 0};
        for (int j = 0; j < 4; j++) {
            int i = ord[j], C = Cs[i];
            a.tmp[j] = tmpb + tpo[i]; a.ctx[j] = cx2 + co[i];
            a.NTC[j] = (long)NT * C;
            a.cum[j] = cum; cum += (int)(((long)NT * C) / 1024);
        }
        a.cum[4] = cum;
        ctxsum_all_kernel<<<cum, 256, 0, stream>>>(a);
    }
    // ---- 8) grouped Wo-all: xb = emb + ctx @ Wo^T ----
    {
        G4 g;
        int cum = 0;
        for (int i = 0; i < 4; i++) {
            const int C = Cs[i];
            const long C2 = (long)C * C;
            g.A[i] = cx2 + co[i]; g.B[i] = (const bf16*)(wp + wb[i] + 4 * C2);
            g.Cv[i] = xball + co[i];
            g.bias[i] = nullptr; g.res[i] = emb[i];
            g.M[i] = NT; g.N[i] = C; g.K[i] = C;
            g.lda[i] = C; g.ldb[i] = C; g.ldc[i] = C;
            g.nbx[i] = (C >= 128) ? C / 128 : 1;
            g.cum[i] = cum; cum += g.nbx[i] * 26;
        }
        g.cum[4] = cum;
        mfma4g<bf16, float><<<cum, 256, 0, stream>>>(g, 0);
    }
    // ---- 9) grouped LN ----
    {
        LR4 a;
        for (int i = 0; i < 4; i++) {
            a.X[i] = xball + co[i]; a.g[i] = fng[i]; a.b[i] = fnb[i];
            a.Y[i] = cx3 + co[i]; a.C[i] = Cs[i];
        }
        ln_rows4_kernel<<<dim3(3136, 4), 256, 0, stream>>>(a);
    }
    // ---- 10) grouped FFN1: hid = gelu(lnx @ w1^T + b1) ----
    {
        G4 g;
        int cum = 0;
        for (int i = 0; i < 4; i++) {
            const int C = Cs[i];
            const long C2 = (long)C * C;
            g.A[i] = cx3 + co[i]; g.B[i] = (const bf16*)(wp + wb[i] + 5 * C2);
            g.Cv[i] = hid + ho[i];
            g.bias[i] = b1[i]; g.res[i] = nullptr;
            g.M[i] = NT; g.N[i] = 4 * C; g.K[i] = C;
            g.lda[i] = C; g.ldb[i] = C; g.ldc[i] = 4 * C;
            g.nbx[i] = 4 * C / 128;
            g.cum[i] = cum; cum += g.nbx[i] * 26;
        }
        g.cum[4] = cum;
        mfma4g<bf16, float><<<cum, 256, 0, stream>>>(g, 1);
    }
    // ---- 11) grouped FFN2: out = xb + hid @ w2^T + b2 (fp32) ----
    {
        G4 g;
        int cum = 0;
        for (int i = 0; i < 4; i++) {
            const int C = Cs[i];
            const long C2 = (long)C * C;
            g.A[i] = hid + ho[i]; g.B[i] = (const bf16*)(wp + wb[i] + 9 * C2);
            g.Cv[i] = out + co[i];
            g.bias[i] = b2[i]; g.res[i] = xball + co[i];
            g.M[i] = NT; g.N[i] = C; g.K[i] = 4 * C;
            g.lda[i] = 4 * C; g.ldb[i] = 4 * C; g.ldc[i] = C;
            g.nbx[i] = (C >= 128) ? C / 128 : 1;
            g.cum[i] = cum; cum += g.nbx[i] * 26;
        }
        g.cum[4] = cum;
        mfma4g<float, bf16><<<cum, 256, 0, stream>>>(g, 0);
    }
}